// Round 7
// baseline (269.298 us; speedup 1.0000x reference)
//
#include <hip/hip_runtime.h>

#define NPTS 65536
#define MM_BLOCKS 64

// ---------------------------------------------------------------------------
// fast tanh: tanh(x) = 1 - 2/(e^{2x}+1). Saturates correctly at +-inf, no NaN.
// ---------------------------------------------------------------------------
__device__ __forceinline__ float fast_tanh(float x) {
  float e = __expf(2.0f * x);
  float r = __builtin_amdgcn_rcpf(e + 1.0f);
  return fmaf(-2.0f, r, 1.0f);
}

// ---------------------------------------------------------------------------
// Univariate order-3 jet -- SCALAR components (round 6 measured: v_pk_fma_f32
// gives ZERO fp32 throughput on CDNA4 (157 TF peak is scalar-FMA-saturable)
// and halves accumulator ILP: 170->193 us.  Keep scalar.)
// 4 float components max (6-comp jets spill, round 2: 1.5 GB scratch).
// ---------------------------------------------------------------------------
struct J3 {
  float v, c1, c2, c3;
  __device__ __forceinline__ static J3 seed(float bias) {
    J3 z; z.v = bias; z.c1 = 0.f; z.c2 = 0.f; z.c3 = 0.f; return z;
  }
  __device__ __forceinline__ void macc(float w, const J3& o) {
    v  = fmaf(w, o.v,  v);
    c1 = fmaf(w, o.c1, c1);
    c2 = fmaf(w, o.c2, c2);
    c3 = fmaf(w, o.c3, c3);
  }
  __device__ __forceinline__ J3 chain() const {
    float s    = fast_tanh(v);
    float fp   = fmaf(-s, s, 1.0f);             // 1 - s^2
    float fpp  = -2.0f * s * fp;                // -2 s (1-s^2)
    float fppp = fmaf(6.0f * s, s, -2.0f) * fp; // (6 s^2 - 2)(1 - s^2)
    J3 r;
    r.v  = s;
    r.c1 = fp * c1;
    r.c2 = fmaf(fpp, c1 * c1, fp * c2);
    r.c3 = fmaf(fppp * c1, c1 * c1, fmaf(3.0f * fpp, c1 * c2, fp * c3));
    return r;
  }
};

// ---------------------------------------------------------------------------
// Mixed second-order jet: value v, first derivs a (dir A), b (dir B), mixed m.
// ---------------------------------------------------------------------------
struct JM {
  float v, a, b, m;
  __device__ __forceinline__ static JM seed(float bias) {
    JM z; z.v = bias; z.a = 0.f; z.b = 0.f; z.m = 0.f; return z;
  }
  __device__ __forceinline__ void macc(float w, const JM& o) {
    v = fmaf(w, o.v, v);
    a = fmaf(w, o.a, a);
    b = fmaf(w, o.b, b);
    m = fmaf(w, o.m, m);
  }
  __device__ __forceinline__ JM chain() const {
    float s   = fast_tanh(v);
    float fp  = fmaf(-s, s, 1.0f);
    float fpp = -2.0f * s * fp;
    JM r;
    r.v = s;
    r.a = fp * a;
    r.b = fp * b;
    r.m = fmaf(fpp, a * b, fp * m);
    return r;
  }
};

// ---------------------------------------------------------------------------
// One dense layer + tanh, reading weights DIRECTLY from the (wave-uniform,
// const __restrict__) kernel-arg pointers with compile-time indices:
// hipcc promotes these to s_load -> weights live in SGPRs, not VGPRs, and
// the LDS staging + ds_read latency path disappears entirely.
// i-OUTER / j-INNER order: for fixed i, W[i][0..19] is contiguous
// (s_load_dwordx16) and the FMA set becomes 20x4 = 80 INDEPENDENT
// accumulation chains -- enough ILP for one wave to self-hide latency
// (r5 measured true VALU busy ~31% with the 4-chain j-outer form).
// v_fmac_f32 vdst, sgpr, vgpr encodes directly (1 SGPR read allowed).
// ---------------------------------------------------------------------------
template <int DIN, int DOUT, class J>
__device__ __forceinline__ void layerG(const float* __restrict__ W,
                                       const float* __restrict__ bias,
                                       const J* in, J* out) {
#pragma unroll
  for (int j = 0; j < DOUT; ++j) out[j] = J::seed(bias[j]);
#pragma unroll
  for (int i = 0; i < DIN; ++i) {
#pragma unroll
    for (int j = 0; j < DOUT; ++j) out[j].macc(W[i * DOUT + j], in[i]);
  }
#pragma unroll
  for (int j = 0; j < DOUT; ++j) out[j] = out[j].chain();
}

// ROUND-0 COPY-BACK FORM -- DO NOT "optimize" into explicit ping-pong.
// Empirical A/B across rounds 0/3/4/5: ONE layerT<20,20> instance in a rolled
// loop + B->A copy keeps the jet arrays in registers (r5: FETCH 725 KB = zero
// spill); THREE unrolled instances spill 440 MB-1 GB.  Copy v_movs are noise.
// Middle-layer pointers via uniform select chain (s_cselect), NOT a
// runtime-indexed pointer array (that would go to scratch).
template <class J>
__device__ __forceinline__ void run_net(
    const float* __restrict__ W1, const float* __restrict__ b1,
    const float* __restrict__ W2, const float* __restrict__ b2,
    const float* __restrict__ W3, const float* __restrict__ b3,
    const float* __restrict__ W4, const float* __restrict__ b4,
    const float* __restrict__ W5, const float* __restrict__ b5,
    const float* __restrict__ W6, const float* __restrict__ b6,
    const float* __restrict__ W7, const float* __restrict__ b7,
    const float* __restrict__ W8, const float* __restrict__ b8,
    J* A, J* O) {
  J B[20];
  layerG<3, 3>(W1, b1, A, B);
  layerG<3, 20>(W2, b2, B, A);
#pragma unroll 1
  for (int l = 0; l < 5; ++l) {   // keep rolled: ONE hot body in I-cache
    const float* Wl = (l == 0) ? W3 : (l == 1) ? W4 : (l == 2) ? W5
                      : (l == 3) ? W6 : W7;
    const float* bl = (l == 0) ? b3 : (l == 1) ? b4 : (l == 2) ? b5
                      : (l == 3) ? b6 : b7;
    layerG<20, 20>(Wl, bl, A, B);
#pragma unroll
    for (int jj = 0; jj < 20; ++jj) A[jj] = B[jj];
  }
  layerG<20, 2>(W8, b8, A, O);
}

// ---------------------------------------------------------------------------
// min/max of X[:,0] via monotone-uint keys; one partial pair per block,
// butterfly-reduced per wave inside pinn_main.
// ---------------------------------------------------------------------------
__device__ __forceinline__ unsigned flipk(float f) {
  unsigned u = __float_as_uint(f);
  return (u & 0x80000000u) ? ~u : (u | 0x80000000u);
}
__device__ __forceinline__ float unflip(unsigned k) {
  unsigned u = (k & 0x80000000u) ? (k ^ 0x80000000u) : ~k;
  return __uint_as_float(u);
}

__global__ void __launch_bounds__(256) mm_reduce(const float* __restrict__ X,
                                                 unsigned* __restrict__ mm) {
  __shared__ unsigned smin[4], smax[4];
  unsigned kmin = 0xFFFFFFFFu, kmax = 0u;
  for (int i = blockIdx.x * 256 + threadIdx.x; i < NPTS; i += gridDim.x * 256) {
    unsigned key = flipk(X[3 * i]);
    kmin = min(kmin, key);
    kmax = max(kmax, key);
  }
#pragma unroll
  for (int o = 32; o > 0; o >>= 1) {
    kmin = min(kmin, (unsigned)__shfl_down((int)kmin, o, 64));
    kmax = max(kmax, (unsigned)__shfl_down((int)kmax, o, 64));
  }
  int wv = threadIdx.x >> 6;
  if ((threadIdx.x & 63) == 0) { smin[wv] = kmin; smax[wv] = kmax; }
  __syncthreads();
  if (threadIdx.x == 0) {
    kmin = min(min(smin[0], smin[1]), min(smin[2], smin[3]));
    kmax = max(max(smax[0], smax[1]), max(smax[2], smax[3]));
    mm[2 * blockIdx.x + 0] = kmin;
    mm[2 * blockIdx.x + 1] = kmax;
  }
}

// ---------------------------------------------------------------------------
// Main kernel: TWO THREADS PER POINT (r5 structure), 3 sequential scalar
// 4-comp passes per thread, seeds parity-selected (no divergence).
// NO LDS, NO BARRIER: weights come from SGPR s_loads (see layerG).
// Residency notes (measured): 252 VGPR -> 1 wave/SIMD (r5, occ 11.5%);
// 128 VGPR cap -> spills (r3).  This round targets ~200-224 VGPR by moving
// weights out of VGPRs -- possibly crossing the 2-waves/SIMD boundary.
// PLAIN __launch_bounds__(256) only: (256,2) caps 128 VGPR -> spills (r3);
// (256,1) removes the cap -> spills (r2).
//   q=0: J3 d=(k,0,0) -> psi_x,psi_xx,psi_xxx,p,p_x; J3 d=(k,k,0) -> S2p,S3p;
//        JM a=x,b=t -> psi_xt
//   q=1: J3 d=(0,k,0) -> psi_y,psi_yy,psi_yyy,p_y;   J3 d=(k,-k,0) -> S2m,S3m;
//        JM a=y,b=t -> psi_yt
// Pair combine: 7 shfl_xor(...,1), even lane assembles + stores.
// ---------------------------------------------------------------------------
__global__ void __launch_bounds__(256) pinn_main(
    const float* __restrict__ X,
    const float* __restrict__ W1, const float* __restrict__ b1,
    const float* __restrict__ W2, const float* __restrict__ b2,
    const float* __restrict__ W3, const float* __restrict__ b3,
    const float* __restrict__ W4, const float* __restrict__ b4,
    const float* __restrict__ W5, const float* __restrict__ b5,
    const float* __restrict__ W6, const float* __restrict__ b6,
    const float* __restrict__ W7, const float* __restrict__ b7,
    const float* __restrict__ W8, const float* __restrict__ b8,
    const float* __restrict__ lam1p, const float* __restrict__ lam2p,
    const unsigned* __restrict__ mm, float* __restrict__ out) {
  const int lane = threadIdx.x & 63;
  const int gid  = blockIdx.x * 256 + threadIdx.x;
  const int pt   = gid >> 1;          // point index (two lanes per point)
  const int q    = gid & 1;           // 0: x-family, 1: y-family

  // global min/max: lane l holds block-partial l, butterfly across the wave
  unsigned pmin = mm[2 * lane + 0];
  unsigned pmax = mm[2 * lane + 1];
#pragma unroll
  for (int o = 1; o < 64; o <<= 1) {
    pmin = min(pmin, (unsigned)__shfl_xor((int)pmin, o, 64));
    pmax = max(pmax, (unsigned)__shfl_xor((int)pmax, o, 64));
  }
  float lb = unflip(pmin);
  float ub = unflip(pmax);
  float kk = 2.0f / (ub - lb);

  float x = X[3 * pt], y = X[3 * pt + 1], tt = X[3 * pt + 2];
  float h0 = fmaf(kk, x - lb, -1.0f);
  float h1 = fmaf(kk, y - lb, -1.0f);
  float h2 = fmaf(kk, tt - lb, -1.0f);

  // pass-A / pass-B first-deriv seeds, parity-selected (cndmask, no branch)
  float a0 = q ? 0.0f : kk, a1 = q ? kk : 0.0f;   // pass A: x-dir / y-dir
  float b1s = q ? -kk : kk;                        // pass B: (k,+-k,0)

  float rc1 = 0, rc2 = 0, rc3 = 0, rpv = 0, rpc = 0;  // pass A results
  float s2 = 0, s3 = 0;                                // pass B results

#pragma unroll 1
  for (int ph = 0; ph < 2; ++ph) {
    J3 A[20], O[2];
    float d0 = ph ? kk  : a0;
    float d1 = ph ? b1s : a1;
    A[0].v = h0; A[0].c1 = d0;  A[0].c2 = 0.f; A[0].c3 = 0.f;
    A[1].v = h1; A[1].c1 = d1;  A[1].c2 = 0.f; A[1].c3 = 0.f;
    A[2].v = h2; A[2].c1 = 0.f; A[2].c2 = 0.f; A[2].c3 = 0.f;
    run_net<J3>(W1, b1, W2, b2, W3, b3, W4, b4, W5, b5, W6, b6, W7, b7,
                W8, b8, A, O);
    if (ph == 0) {
      rc1 = O[0].c1; rc2 = O[0].c2; rc3 = O[0].c3;
      rpv = O[1].v;  rpc = O[1].c1;
    } else {
      s2 = O[0].c2; s3 = O[0].c3;
    }
  }

  float rm;
  {
    JM A[20], O[2];
    A[0].v = h0; A[0].a = a0;  A[0].b = 0.f; A[0].m = 0.f;
    A[1].v = h1; A[1].a = a1;  A[1].b = 0.f; A[1].m = 0.f;
    A[2].v = h2; A[2].a = 0.f; A[2].b = kk;  A[2].m = 0.f;
    run_net<JM>(W1, b1, W2, b2, W3, b3, W4, b4, W5, b5, W6, b6, W7, b7,
                W8, b8, A, O);
    rm = O[0].m;   // psi_xt (q=0) / psi_yt (q=1)
  }

  // pair exchange: even lane receives the y-family values
  float psi_y   = __shfl_xor(rc1, 1, 64);
  float psi_yy  = __shfl_xor(rc2, 1, 64);
  float psi_yyy = __shfl_xor(rc3, 1, 64);
  float p_y     = __shfl_xor(rpc, 1, 64);
  float S2m     = __shfl_xor(s2, 1, 64);
  float S3m     = __shfl_xor(s3, 1, 64);
  float psi_yt  = __shfl_xor(rm, 1, 64);

  if (q == 0) {
    float psi_x = rc1, psi_xx = rc2, psi_xxx = rc3;
    float p_val = rpv, p_x = rpc;
    float S2p = s2, S3p = s3;
    float psi_xt = rm;

    // polarization identities
    float psi_xy  = 0.25f * (S2p - S2m);
    float psi_xxy = (S3p - S3m - 2.0f * psi_yyy) * (1.0f / 6.0f);
    float psi_xyy = (S3p + S3m - 2.0f * psi_xxx) * (1.0f / 6.0f);

    float u = psi_y, vv = -psi_x;
    float u_x = psi_xy,  u_y = psi_yy,  u_t = psi_yt;
    float v_x = -psi_xx, v_y = -psi_xy, v_t = -psi_xt;
    float u_xx = psi_xxy,  u_yy = psi_yyy;
    float v_xx = -psi_xxx, v_yy = -psi_xyy;

    float lam1 = lam1p[0], lam2 = lam2p[0];
    float f_u = u_t + lam1 * (u * u_x + vv * u_y) + p_x - lam2 * (u_xx + u_yy);
    float f_v = v_t + lam1 * (u * v_x + vv * v_y) + p_y - lam2 * (v_xx + v_yy);

    out[pt] = u;
    out[NPTS + pt] = vv;
    out[2 * NPTS + pt] = p_val;
    out[3 * NPTS + pt] = f_u;
    out[4 * NPTS + pt] = f_v;
  }
}

extern "C" void kernel_launch(void* const* d_in, const int* in_sizes, int n_in,
                              void* d_out, int out_size, void* d_ws, size_t ws_size,
                              hipStream_t stream) {
  (void)in_sizes; (void)n_in; (void)out_size; (void)ws_size;
  const float* X = (const float*)d_in[0];
  const float* W[8]; const float* B[8];
  for (int i = 0; i < 8; ++i) {
    W[i] = (const float*)d_in[1 + 2 * i];
    B[i] = (const float*)d_in[2 + 2 * i];
  }
  const float* lam1 = (const float*)d_in[17];
  const float* lam2 = (const float*)d_in[18];
  unsigned* mm = (unsigned*)d_ws;
  float* out = (float*)d_out;

  hipLaunchKernelGGL(mm_reduce, dim3(MM_BLOCKS), dim3(256), 0, stream, X, mm);
  hipLaunchKernelGGL(pinn_main, dim3(2 * NPTS / 256), dim3(256), 0, stream,
                     X, W[0], B[0], W[1], B[1], W[2], B[2], W[3], B[3],
                     W[4], B[4], W[5], B[5], W[6], B[6], W[7], B[7],
                     lam1, lam2, mm, out);
}

// Round 8
// 254.244 us; speedup vs baseline: 1.0592x; 1.0592x over previous
//
#include <hip/hip_runtime.h>

#define NPTS 65536
#define MM_BLOCKS 64

// ---------------------------------------------------------------------------
// fast tanh: tanh(x) = 1 - 2/(e^{2x}+1). Saturates correctly at +-inf, no NaN.
// ---------------------------------------------------------------------------
__device__ __forceinline__ float fast_tanh(float x) {
  float e = __expf(2.0f * x);
  float r = __builtin_amdgcn_rcpf(e + 1.0f);
  return fmaf(-2.0f, r, 1.0f);
}

// ---------------------------------------------------------------------------
// Scalar 4-comp jets (r6 measured: v_pk_fma_f32 is zero-gain on CDNA4 fp32
// and halves ILP; r2 measured: 6-comp jets spill GBs.  Keep scalar, 4 comps.)
// ---------------------------------------------------------------------------
struct J3 {
  float v, c1, c2, c3;
  __device__ __forceinline__ static J3 seed(float bias) {
    J3 z; z.v = bias; z.c1 = 0.f; z.c2 = 0.f; z.c3 = 0.f; return z;
  }
  __device__ __forceinline__ void macc(float w, const J3& o) {
    v  = fmaf(w, o.v,  v);
    c1 = fmaf(w, o.c1, c1);
    c2 = fmaf(w, o.c2, c2);
    c3 = fmaf(w, o.c3, c3);
  }
  __device__ __forceinline__ J3 chain() const {
    float s    = fast_tanh(v);
    float fp   = fmaf(-s, s, 1.0f);             // 1 - s^2
    float fpp  = -2.0f * s * fp;                // -2 s (1-s^2)
    float fppp = fmaf(6.0f * s, s, -2.0f) * fp; // (6 s^2 - 2)(1 - s^2)
    J3 r;
    r.v  = s;
    r.c1 = fp * c1;
    r.c2 = fmaf(fpp, c1 * c1, fp * c2);
    r.c3 = fmaf(fppp * c1, c1 * c1, fmaf(3.0f * fpp, c1 * c2, fp * c3));
    return r;
  }
};

struct JM {
  float v, a, b, m;
  __device__ __forceinline__ static JM seed(float bias) {
    JM z; z.v = bias; z.a = 0.f; z.b = 0.f; z.m = 0.f; return z;
  }
  __device__ __forceinline__ void macc(float w, const JM& o) {
    v = fmaf(w, o.v, v);
    a = fmaf(w, o.a, a);
    b = fmaf(w, o.b, b);
    m = fmaf(w, o.m, m);
  }
  __device__ __forceinline__ JM chain() const {
    float s   = fast_tanh(v);
    float fp  = fmaf(-s, s, 1.0f);
    float fpp = -2.0f * s * fp;
    JM r;
    r.v = s;
    r.a = fp * a;
    r.b = fp * b;
    r.m = fmaf(fpp, a * b, fp * m);
    return r;
  }
};

// partner-half exchange: lane^2 (same q, other hidden-half)
__device__ __forceinline__ J3 shfl2(const J3& o) {
  J3 r;
  r.v  = __shfl_xor(o.v,  2, 64);
  r.c1 = __shfl_xor(o.c1, 2, 64);
  r.c2 = __shfl_xor(o.c2, 2, 64);
  r.c3 = __shfl_xor(o.c3, 2, 64);
  return r;
}
__device__ __forceinline__ JM shfl2(const JM& o) {
  JM r;
  r.v = __shfl_xor(o.v, 2, 64);
  r.a = __shfl_xor(o.a, 2, 64);
  r.b = __shfl_xor(o.b, 2, 64);
  r.m = __shfl_xor(o.m, 2, 64);
  return r;
}

// ---------------------------------------------------------------------------
// Split 20->20 layer: this thread owns hidden units [hb, hb+10) (hb = 0/10).
// Streams partner's 10 inputs via shfl2 one unit at a time (4-float temp, no
// second buffer).  ob/pb are precomputed weight bases: own row i=hb+ii,
// partner row i=(10-hb)+ii, output column base hb; W row-major [i*20+j].
// ii loop MUST be fully unrolled: A[ii] with runtime index goes to scratch.
// ---------------------------------------------------------------------------
template <class J>
__device__ __forceinline__ void layer20_split(const float* __restrict__ W,
                                              const float* __restrict__ bias,
                                              int hb, int ob, int pb,
                                              const J* A, J* B) {
#pragma unroll
  for (int j = 0; j < 10; ++j) B[j] = J::seed(bias[hb + j]);
#pragma unroll
  for (int ii = 0; ii < 10; ++ii) {
    J recv = shfl2(A[ii]);
    const float* Wo = W + ob + 20 * ii;   // own row, own column half
    const float* Wp = W + pb + 20 * ii;   // partner row, own column half
#pragma unroll
    for (int j = 0; j < 10; ++j) {
      B[j].macc(Wo[j], A[ii]);
      B[j].macc(Wp[j], recv);
    }
  }
#pragma unroll
  for (int j = 0; j < 10; ++j) B[j] = B[j].chain();
}

// LDS layout (floats, NATURAL row-major, straight copy -- no transpose):
// L1 W@0(9) b@9(3) | L2 W@12(60) b@72(20) | L3..L7 stride 420: W@92+420l(400)
// b@+400(20) | L8 W@2192(40) b@2232(2)
#define LDS_W_FLOATS 2234

// COPY-BACK FORM of the rolled middle loop -- r0/r3/r4/r5 A/B: one unrolled
// 20x20 body + B->A copy keeps buffers in registers; multiple unrolled
// instances spill GBs.  Each thread's final output is the single unit j=hh
// of L8 (hh=0 -> psi jet, hh=1 -> p jet).
template <class J>
__device__ __forceinline__ void run_net(const float* __restrict__ w,
                                        int hh, int hb, int ob, int pb,
                                        const J* in3, J& O) {
  J T[3];
#pragma unroll
  for (int j = 0; j < 3; ++j) {               // L1 3->3, duplicated (local)
    J z = J::seed(w[9 + j]);
#pragma unroll
    for (int i = 0; i < 3; ++i) z.macc(w[i * 3 + j], in3[i]);
    T[j] = z.chain();
  }
  J A[10], B[10];
#pragma unroll
  for (int j = 0; j < 10; ++j) {              // L2 3->20, split (local inputs)
    J z = J::seed(w[72 + hb + j]);
#pragma unroll
    for (int i = 0; i < 3; ++i) z.macc(w[12 + i * 20 + hb + j], T[i]);
    A[j] = z.chain();
  }
#pragma unroll 1
  for (int l = 0; l < 5; ++l) {               // L3..L7, one hot body
    const float* Wl = w + 92 + l * 420;
    layer20_split(Wl, Wl + 400, hb, ob, pb, A, B);
#pragma unroll
    for (int jj = 0; jj < 10; ++jj) A[jj] = B[jj];
  }
  {                                           // L8 20->2: output j = hh
    J z = J::seed(w[2232 + hh]);
#pragma unroll
    for (int ii = 0; ii < 10; ++ii) {
      J recv = shfl2(A[ii]);
      z.macc(w[2192 + (hb + ii) * 2 + hh], A[ii]);
      z.macc(w[2192 + (10 - hb + ii) * 2 + hh], recv);
    }
    O = z.chain();
  }
}

// ---------------------------------------------------------------------------
// min/max of X[:,0] via monotone-uint keys; one partial pair per block,
// butterfly-reduced per wave inside pinn_main.
// ---------------------------------------------------------------------------
__device__ __forceinline__ unsigned flipk(float f) {
  unsigned u = __float_as_uint(f);
  return (u & 0x80000000u) ? ~u : (u | 0x80000000u);
}
__device__ __forceinline__ float unflip(unsigned k) {
  unsigned u = (k & 0x80000000u) ? (k ^ 0x80000000u) : ~k;
  return __uint_as_float(u);
}

__global__ void __launch_bounds__(256) mm_reduce(const float* __restrict__ X,
                                                 unsigned* __restrict__ mm) {
  __shared__ unsigned smin[4], smax[4];
  unsigned kmin = 0xFFFFFFFFu, kmax = 0u;
  for (int i = blockIdx.x * 256 + threadIdx.x; i < NPTS; i += gridDim.x * 256) {
    unsigned key = flipk(X[3 * i]);
    kmin = min(kmin, key);
    kmax = max(kmax, key);
  }
#pragma unroll
  for (int o = 32; o > 0; o >>= 1) {
    kmin = min(kmin, (unsigned)__shfl_down((int)kmin, o, 64));
    kmax = max(kmax, (unsigned)__shfl_down((int)kmax, o, 64));
  }
  int wv = threadIdx.x >> 6;
  if ((threadIdx.x & 63) == 0) { smin[wv] = kmin; smax[wv] = kmax; }
  __syncthreads();
  if (threadIdx.x == 0) {
    kmin = min(min(smin[0], smin[1]), min(smin[2], smin[3]));
    kmax = max(max(smax[0], smax[1]), max(smax[2], smax[3]));
    mm[2 * blockIdx.x + 0] = kmin;
    mm[2 * blockIdx.x + 1] = kmax;
  }
}

// ---------------------------------------------------------------------------
// Main kernel: FOUR LANES PER POINT.  bit0 q = pass family (x/y, r5 scheme),
// bit1 hh = hidden-half (units 0-9 / 10-19).  Per-thread jet buffers halve to
// A[10]+B[10] = 80 floats, targeting the MEASURED gfx950 residency cliff:
// VGPR in (128,256] allocates a 256 slot -> 1 wave/SIMD (r5: 252 -> 11.5%,
// r7: 148 -> 11.6%); VGPR <= 128 -> 2 blocks/CU (r3: 128 -> 22%).
// __launch_bounds__(256,2) forces the 128 cap; unlike r3 (160+ live floats)
// the state now FITS, so no spill storm is expected -- falsifier: FETCH
// ballooning to 100s of MB.  All lanes run identical code (seeds and column
// bases are data); exchanges are 4 shfl_xor per streamed unit.
//   q=0: J3 d=(k,0,0): psi_x/xx/xxx + p,p_x | J3 d=(k,k,0): S2p,S3p | JM x,t
//   q=1: J3 d=(0,k,0): psi_y/yy/yyy + p_y   | J3 d=(k,-k,0): S2m,S3m | JM y,t
//   hh=0 lanes end with the psi jet, hh=1 lanes with the p jet.
// Final assembly: 9 shfl_xor (1: q-partner, 2: hh-partner, 3: diagonal),
// lane (q=0,hh=0) stores.
// ---------------------------------------------------------------------------
__global__ void __launch_bounds__(256, 2) pinn_main(
    const float* __restrict__ X,
    const float* W1, const float* b1, const float* W2, const float* b2,
    const float* W3, const float* b3, const float* W4, const float* b4,
    const float* W5, const float* b5, const float* W6, const float* b6,
    const float* W7, const float* b7, const float* W8, const float* b8,
    const float* lam1p, const float* lam2p, const unsigned* __restrict__ mm,
    float* __restrict__ out) {
  __shared__ float w[LDS_W_FLOATS];
  {
    const float* Wsrc[8] = {W1, W2, W3, W4, W5, W6, W7, W8};
    const float* bsrc[8] = {b1, b2, b3, b4, b5, b6, b7, b8};
    const int nwA[8]  = {9, 60, 400, 400, 400, 400, 400, 40};
    const int nbA[8]  = {3, 20, 20, 20, 20, 20, 20, 2};
    const int offW[8] = {0, 12, 92, 512, 932, 1352, 1772, 2192};
    const int offB[8] = {9, 72, 492, 912, 1332, 1752, 2172, 2232};
#pragma unroll
    for (int a = 0; a < 8; ++a) {
      for (int s = threadIdx.x; s < nwA[a]; s += 256) w[offW[a] + s] = Wsrc[a][s];
      for (int s = threadIdx.x; s < nbA[a]; s += 256) w[offB[a] + s] = bsrc[a][s];
    }
  }

  const int lane = threadIdx.x & 63;
  const int gid  = blockIdx.x * 256 + threadIdx.x;
  const int pt   = gid >> 2;           // point index (four lanes per point)
  const int q    = gid & 1;            // pass family
  const int hh   = (gid >> 1) & 1;     // hidden half
  const int hb   = 10 * hh;            // unit base
  const int ob   = 21 * hb;            // own-row weight base (row hb+ii, col hb)
  const int pb   = 200 - 19 * hb;      // partner-row weight base

  // global min/max: lane l holds block-partial l, butterfly across the wave
  unsigned pmin = mm[2 * lane + 0];
  unsigned pmax = mm[2 * lane + 1];
#pragma unroll
  for (int o = 1; o < 64; o <<= 1) {
    pmin = min(pmin, (unsigned)__shfl_xor((int)pmin, o, 64));
    pmax = max(pmax, (unsigned)__shfl_xor((int)pmax, o, 64));
  }
  float lb = unflip(pmin);
  float ub = unflip(pmax);
  float kk = 2.0f / (ub - lb);

  float x = X[3 * pt], y = X[3 * pt + 1], tt = X[3 * pt + 2];
  float h0 = fmaf(kk, x - lb, -1.0f);
  float h1 = fmaf(kk, y - lb, -1.0f);
  float h2 = fmaf(kk, tt - lb, -1.0f);

  __syncthreads();  // weights staged

  // seeds, parity-selected (cndmask, no branch)
  float a0 = q ? 0.0f : kk, a1 = q ? kk : 0.0f;   // pass A: x-dir / y-dir
  float b1s = q ? -kk : kk;                        // pass B: (k,+-k,0)

  float rAv, rAc1, rAc2, rAc3;   // pass A jet (psi-jet on hh=0, p-jet on hh=1)
  float s2, s3;                  // pass B c2,c3
  float rm;                      // JM mixed

  {
    J3 I[3], O;
    I[0].v = h0; I[0].c1 = a0;  I[0].c2 = 0.f; I[0].c3 = 0.f;
    I[1].v = h1; I[1].c1 = a1;  I[1].c2 = 0.f; I[1].c3 = 0.f;
    I[2].v = h2; I[2].c1 = 0.f; I[2].c2 = 0.f; I[2].c3 = 0.f;
    run_net<J3>(w, hh, hb, ob, pb, I, O);
    rAv = O.v; rAc1 = O.c1; rAc2 = O.c2; rAc3 = O.c3;
  }
  {
    J3 I[3], O;
    I[0].v = h0; I[0].c1 = kk;  I[0].c2 = 0.f; I[0].c3 = 0.f;
    I[1].v = h1; I[1].c1 = b1s; I[1].c2 = 0.f; I[1].c3 = 0.f;
    I[2].v = h2; I[2].c1 = 0.f; I[2].c2 = 0.f; I[2].c3 = 0.f;
    run_net<J3>(w, hh, hb, ob, pb, I, O);
    s2 = O.c2; s3 = O.c3;
  }
  {
    JM I[3], O;
    I[0].v = h0; I[0].a = a0;  I[0].b = 0.f; I[0].m = 0.f;
    I[1].v = h1; I[1].a = a1;  I[1].b = 0.f; I[1].m = 0.f;
    I[2].v = h2; I[2].a = 0.f; I[2].b = kk;  I[2].m = 0.f;
    run_net<JM>(w, hh, hb, ob, pb, I, O);
    rm = O.m;
  }

  // assembly exchanges (all lanes execute; writer = lane with q=0,hh=0)
  float psi_y   = __shfl_xor(rAc1, 1, 64);   // from (1,0): psi-jet along y
  float psi_yy  = __shfl_xor(rAc2, 1, 64);
  float psi_yyy = __shfl_xor(rAc3, 1, 64);
  float S2m     = __shfl_xor(s2, 1, 64);
  float S3m     = __shfl_xor(s3, 1, 64);
  float psi_yt  = __shfl_xor(rm, 1, 64);
  float p_val   = __shfl_xor(rAv, 2, 64);    // from (0,1): p-jet along x
  float p_x     = __shfl_xor(rAc1, 2, 64);
  float p_y     = __shfl_xor(rAc1, 3, 64);   // from (1,1): p-jet along y

  if ((gid & 3) == 0) {
    float psi_x = rAc1, psi_xx = rAc2, psi_xxx = rAc3;
    float S2p = s2, S3p = s3;
    float psi_xt = rm;

    // polarization identities
    float psi_xy  = 0.25f * (S2p - S2m);
    float psi_xxy = (S3p - S3m - 2.0f * psi_yyy) * (1.0f / 6.0f);
    float psi_xyy = (S3p + S3m - 2.0f * psi_xxx) * (1.0f / 6.0f);

    float u = psi_y, vv = -psi_x;
    float u_x = psi_xy,  u_y = psi_yy,  u_t = psi_yt;
    float v_x = -psi_xx, v_y = -psi_xy, v_t = -psi_xt;
    float u_xx = psi_xxy,  u_yy = psi_yyy;
    float v_xx = -psi_xxx, v_yy = -psi_xyy;

    float lam1 = lam1p[0], lam2 = lam2p[0];
    float f_u = u_t + lam1 * (u * u_x + vv * u_y) + p_x - lam2 * (u_xx + u_yy);
    float f_v = v_t + lam1 * (u * v_x + vv * v_y) + p_y - lam2 * (v_xx + v_yy);

    out[pt] = u;
    out[NPTS + pt] = vv;
    out[2 * NPTS + pt] = p_val;
    out[3 * NPTS + pt] = f_u;
    out[4 * NPTS + pt] = f_v;
  }
}

extern "C" void kernel_launch(void* const* d_in, const int* in_sizes, int n_in,
                              void* d_out, int out_size, void* d_ws, size_t ws_size,
                              hipStream_t stream) {
  (void)in_sizes; (void)n_in; (void)out_size; (void)ws_size;
  const float* X = (const float*)d_in[0];
  const float* W[8]; const float* B[8];
  for (int i = 0; i < 8; ++i) {
    W[i] = (const float*)d_in[1 + 2 * i];
    B[i] = (const float*)d_in[2 + 2 * i];
  }
  const float* lam1 = (const float*)d_in[17];
  const float* lam2 = (const float*)d_in[18];
  unsigned* mm = (unsigned*)d_ws;
  float* out = (float*)d_out;

  hipLaunchKernelGGL(mm_reduce, dim3(MM_BLOCKS), dim3(256), 0, stream, X, mm);
  hipLaunchKernelGGL(pinn_main, dim3(4 * NPTS / 256), dim3(256), 0, stream,
                     X, W[0], B[0], W[1], B[1], W[2], B[2], W[3], B[3],
                     W[4], B[4], W[5], B[5], W[6], B[6], W[7], B[7],
                     lam1, lam2, mm, out);
}

// Round 9
// 249.291 us; speedup vs baseline: 1.0803x; 1.0199x over previous
//
#include <hip/hip_runtime.h>

#define NPTS 65536
#define MM_BLOCKS 64

// ---------------------------------------------------------------------------
// fast tanh: tanh(x) = 1 - 2/(e^{2x}+1). Saturates correctly at +-inf, no NaN.
// ---------------------------------------------------------------------------
__device__ __forceinline__ float fast_tanh(float x) {
  float e = __expf(2.0f * x);
  float r = __builtin_amdgcn_rcpf(e + 1.0f);
  return fmaf(-2.0f, r, 1.0f);
}

// ---------------------------------------------------------------------------
// Scalar 4-comp jets (r6: v_pk_fma_f32 is zero-gain on CDNA4 fp32 and halves
// ILP; r2: 6-comp jets spill GBs.  Keep scalar, 4 comps).
// ---------------------------------------------------------------------------
struct J3 {
  float v, c1, c2, c3;
  __device__ __forceinline__ static J3 seed(float bias) {
    J3 z; z.v = bias; z.c1 = 0.f; z.c2 = 0.f; z.c3 = 0.f; return z;
  }
  __device__ __forceinline__ void macc(float w, const J3& o) {
    v  = fmaf(w, o.v,  v);
    c1 = fmaf(w, o.c1, c1);
    c2 = fmaf(w, o.c2, c2);
    c3 = fmaf(w, o.c3, c3);
  }
  __device__ __forceinline__ J3 chain() const {
    float s    = fast_tanh(v);
    float fp   = fmaf(-s, s, 1.0f);             // 1 - s^2
    float fpp  = -2.0f * s * fp;                // -2 s (1-s^2)
    float fppp = fmaf(6.0f * s, s, -2.0f) * fp; // (6 s^2 - 2)(1 - s^2)
    J3 r;
    r.v  = s;
    r.c1 = fp * c1;
    r.c2 = fmaf(fpp, c1 * c1, fp * c2);
    r.c3 = fmaf(fppp * c1, c1 * c1, fmaf(3.0f * fpp, c1 * c2, fp * c3));
    return r;
  }
};

struct JM {
  float v, a, b, m;
  __device__ __forceinline__ static JM seed(float bias) {
    JM z; z.v = bias; z.a = 0.f; z.b = 0.f; z.m = 0.f; return z;
  }
  __device__ __forceinline__ void macc(float w, const JM& o) {
    v = fmaf(w, o.v, v);
    a = fmaf(w, o.a, a);
    b = fmaf(w, o.b, b);
    m = fmaf(w, o.m, m);
  }
  __device__ __forceinline__ JM chain() const {
    float s   = fast_tanh(v);
    float fp  = fmaf(-s, s, 1.0f);
    float fpp = -2.0f * s * fp;
    JM r;
    r.v = s;
    r.a = fp * a;
    r.b = fp * b;
    r.m = fmaf(fpp, a * b, fp * m);
    return r;
  }
};

// lane exchange of a whole jet (mask is compile-time; masks 1/2/3 stay inside
// a quad -- the hot path uses only those)
template <int M> __device__ __forceinline__ J3 shflx(const J3& o) {
  J3 r;
  r.v  = __shfl_xor(o.v,  M, 64);
  r.c1 = __shfl_xor(o.c1, M, 64);
  r.c2 = __shfl_xor(o.c2, M, 64);
  r.c3 = __shfl_xor(o.c3, M, 64);
  return r;
}
template <int M> __device__ __forceinline__ JM shflx(const JM& o) {
  JM r;
  r.v = __shfl_xor(o.v, M, 64);
  r.a = __shfl_xor(o.a, M, 64);
  r.b = __shfl_xor(o.b, M, 64);
  r.m = __shfl_xor(o.m, M, 64);
  return r;
}
template <int M> __device__ __forceinline__ void redsum(J3& z) {
  z.v  += __shfl_xor(z.v,  M, 64);
  z.c1 += __shfl_xor(z.c1, M, 64);
  z.c2 += __shfl_xor(z.c2, M, 64);
  z.c3 += __shfl_xor(z.c3, M, 64);
}
template <int M> __device__ __forceinline__ void redsum(JM& z) {
  z.v += __shfl_xor(z.v, M, 64);
  z.a += __shfl_xor(z.a, M, 64);
  z.b += __shfl_xor(z.b, M, 64);
  z.m += __shfl_xor(z.m, M, 64);
}

// ---------------------------------------------------------------------------
// Quarter-split 20->20 layer: this lane owns hidden units [hb, hb+5).
// Partner activations stream in via intra-quad shfl_xor (one recv live at a
// time -- liveness discipline, r8 overflowed the 128 cap with batched recvs).
// W row-major [i*20+j]; 4 base pointers, all other addressing is immediates.
// ---------------------------------------------------------------------------
template <class J>
__device__ __forceinline__ void layer20_q(const float* __restrict__ W,
                                          const float* __restrict__ bias,
                                          int hb, int hb1, int hb2, int hb3,
                                          const J* A, J* B) {
  const float* B0 = W + hb  * 20 + hb;   // own rows
  const float* B1 = W + hb1 * 20 + hb;   // quad-partner ^1 rows
  const float* B2 = W + hb2 * 20 + hb;   // quad-partner ^2 rows
  const float* B3 = W + hb3 * 20 + hb;   // quad-partner ^3 rows
#pragma unroll
  for (int j = 0; j < 5; ++j) B[j] = J::seed(bias[hb + j]);
#pragma unroll
  for (int ii = 0; ii < 5; ++ii) {
    J s = A[ii];
#pragma unroll
    for (int j = 0; j < 5; ++j) B[j].macc(B0[ii * 20 + j], s);
    s = shflx<1>(A[ii]);
#pragma unroll
    for (int j = 0; j < 5; ++j) B[j].macc(B1[ii * 20 + j], s);
    s = shflx<2>(A[ii]);
#pragma unroll
    for (int j = 0; j < 5; ++j) B[j].macc(B2[ii * 20 + j], s);
    s = shflx<3>(A[ii]);
#pragma unroll
    for (int j = 0; j < 5; ++j) B[j].macc(B3[ii * 20 + j], s);
  }
#pragma unroll
  for (int j = 0; j < 5; ++j) B[j] = B[j].chain();
}

// LDS layout (floats, NATURAL row-major, straight copy):
// L1 W@0(9) b@9(3) | L2 W@12(60) b@72(20) | L3..L7 stride 420: W@92+420l(400)
// b@+400(20) | L8 W@2192(40) b@2232(2)
#define LDS_W_FLOATS 2234

// COPY-BACK mid loop (r0/r4/r5 A/B: one unrolled body + B->A copy = zero
// spill; multiple unrolled 20x20 instances = GB-scale spill).  L8: per-lane
// partial dot over own 5 units, 2-stage intra-quad butterfly sum, bias added
// post-reduction, then tanh chain.
template <class J>
__device__ __forceinline__ void run_net(const float* __restrict__ w,
                                        int hb, int hb1, int hb2, int hb3,
                                        const J* in3, J& Opsi, J& Op) {
  J A[5], B[5];
  {
    J T[3];
#pragma unroll
    for (int j = 0; j < 3; ++j) {               // L1 3->3, duplicated
      J z = J::seed(w[9 + j]);
#pragma unroll
      for (int i = 0; i < 3; ++i) z.macc(w[i * 3 + j], in3[i]);
      T[j] = z.chain();
    }
#pragma unroll
    for (int j = 0; j < 5; ++j) {               // L2 3->20, split by quarter
      J z = J::seed(w[72 + hb + j]);
#pragma unroll
      for (int i = 0; i < 3; ++i) z.macc(w[12 + i * 20 + hb + j], T[i]);
      A[j] = z.chain();
    }
  }
#pragma unroll 1
  for (int l = 0; l < 5; ++l) {                 // L3..L7, one hot body
    const float* Wl = w + 92 + l * 420;
    layer20_q(Wl, Wl + 400, hb, hb1, hb2, hb3, A, B);
#pragma unroll
    for (int jj = 0; jj < 5; ++jj) A[jj] = B[jj];
  }
  J z0 = J::seed(0.f), z1 = J::seed(0.f);       // L8 20->2 partials
#pragma unroll
  for (int ii = 0; ii < 5; ++ii) {
    z0.macc(w[2192 + (hb + ii) * 2 + 0], A[ii]);
    z1.macc(w[2192 + (hb + ii) * 2 + 1], A[ii]);
  }
  redsum<1>(z0); redsum<2>(z0);
  redsum<1>(z1); redsum<2>(z1);
  z0.v += w[2232];
  z1.v += w[2233];
  Opsi = z0.chain();
  Op   = z1.chain();
}

// ---------------------------------------------------------------------------
// min/max of X[:,0] via monotone-uint keys; one partial pair per block,
// butterfly-reduced per wave inside pinn_main.
// ---------------------------------------------------------------------------
__device__ __forceinline__ unsigned flipk(float f) {
  unsigned u = __float_as_uint(f);
  return (u & 0x80000000u) ? ~u : (u | 0x80000000u);
}
__device__ __forceinline__ float unflip(unsigned k) {
  unsigned u = (k & 0x80000000u) ? (k ^ 0x80000000u) : ~k;
  return __uint_as_float(u);
}

__global__ void __launch_bounds__(256) mm_reduce(const float* __restrict__ X,
                                                 unsigned* __restrict__ mm) {
  __shared__ unsigned smin[4], smax[4];
  unsigned kmin = 0xFFFFFFFFu, kmax = 0u;
  for (int i = blockIdx.x * 256 + threadIdx.x; i < NPTS; i += gridDim.x * 256) {
    unsigned key = flipk(X[3 * i]);
    kmin = min(kmin, key);
    kmax = max(kmax, key);
  }
#pragma unroll
  for (int o = 32; o > 0; o >>= 1) {
    kmin = min(kmin, (unsigned)__shfl_down((int)kmin, o, 64));
    kmax = max(kmax, (unsigned)__shfl_down((int)kmax, o, 64));
  }
  int wv = threadIdx.x >> 6;
  if ((threadIdx.x & 63) == 0) { smin[wv] = kmin; smax[wv] = kmax; }
  __syncthreads();
  if (threadIdx.x == 0) {
    kmin = min(min(smin[0], smin[1]), min(smin[2], smin[3]));
    kmax = max(max(smax[0], smax[1]), max(smax[2], smax[3]));
    mm[2 * blockIdx.x + 0] = kmin;
    mm[2 * blockIdx.x + 1] = kmax;
  }
}

// ---------------------------------------------------------------------------
// Main kernel: EIGHT LANES PER POINT.  bits0-1 = hidden QUARTER Q (units
// 5Q..5Q+4), bit2 = pass family q.  Per-thread jet buffers = A[5]+B[5] = 40
// floats; hot-loop live ~90 -> real headroom under the 128-VGPR cap (r8's
// half-split sat at ~120 and spilled 860B/thread; r5/r7 showed >128 VGPR =
// 1 wave/SIMD).  Q in the LOW bits makes every hot shuffle intra-quad
// (masks 1/2/3); only the final assembly crosses quads (mask 4).
//   q=0: J3 d=(k,0,0): psi_x/xx/xxx + p,p_x | J3 d=(k,k,0): S2p,S3p | JM x,t
//   q=1: J3 d=(0,k,0): psi_y/yy/yyy + p_y   | J3 d=(k,-k,0): S2m,S3m | JM y,t
// After L8's butterfly, ALL lanes hold their family's full psi/p jets;
// 7 mask-4 shfls fetch the other family; lane (gid&7)==0 stores.
// ---------------------------------------------------------------------------
__global__ void __launch_bounds__(256, 2) pinn_main(
    const float* __restrict__ X,
    const float* W1, const float* b1, const float* W2, const float* b2,
    const float* W3, const float* b3, const float* W4, const float* b4,
    const float* W5, const float* b5, const float* W6, const float* b6,
    const float* W7, const float* b7, const float* W8, const float* b8,
    const float* lam1p, const float* lam2p, const unsigned* __restrict__ mm,
    float* __restrict__ out) {
  __shared__ float w[LDS_W_FLOATS];
  {
    const float* Wsrc[8] = {W1, W2, W3, W4, W5, W6, W7, W8};
    const float* bsrc[8] = {b1, b2, b3, b4, b5, b6, b7, b8};
    const int nwA[8]  = {9, 60, 400, 400, 400, 400, 400, 40};
    const int nbA[8]  = {3, 20, 20, 20, 20, 20, 20, 2};
    const int offW[8] = {0, 12, 92, 512, 932, 1352, 1772, 2192};
    const int offB[8] = {9, 72, 492, 912, 1332, 1752, 2172, 2232};
#pragma unroll
    for (int a = 0; a < 8; ++a) {
      for (int s = threadIdx.x; s < nwA[a]; s += 256) w[offW[a] + s] = Wsrc[a][s];
      for (int s = threadIdx.x; s < nbA[a]; s += 256) w[offB[a] + s] = bsrc[a][s];
    }
  }

  const int lane = threadIdx.x & 63;
  const int gid  = blockIdx.x * 256 + threadIdx.x;
  const int pt   = gid >> 3;           // point index (eight lanes per point)
  const int Q    = gid & 3;            // hidden quarter
  const int q    = (gid >> 2) & 1;     // pass family
  const int hb   = 5 * Q;
  const int hb1  = 5 * (Q ^ 1);
  const int hb2  = 5 * (Q ^ 2);
  const int hb3  = 5 * (Q ^ 3);

  // global min/max: lane l holds block-partial l, butterfly across the wave
  unsigned pmin = mm[2 * lane + 0];
  unsigned pmax = mm[2 * lane + 1];
#pragma unroll
  for (int o = 1; o < 64; o <<= 1) {
    pmin = min(pmin, (unsigned)__shfl_xor((int)pmin, o, 64));
    pmax = max(pmax, (unsigned)__shfl_xor((int)pmax, o, 64));
  }
  float lb = unflip(pmin);
  float ub = unflip(pmax);
  float kk = 2.0f / (ub - lb);

  float x = X[3 * pt], y = X[3 * pt + 1], tt = X[3 * pt + 2];
  float h0 = fmaf(kk, x - lb, -1.0f);
  float h1 = fmaf(kk, y - lb, -1.0f);
  float h2 = fmaf(kk, tt - lb, -1.0f);

  __syncthreads();  // weights staged

  // seeds, family-selected (cndmask, no branch)
  float a0 = q ? 0.0f : kk, a1 = q ? kk : 0.0f;   // pass A: x-dir / y-dir
  float b1s = q ? -kk : kk;                        // pass B: (k,+-k,0)

  float rc1, rc2, rc3, rpv, rpc;  // pass A: psi jet c1-c3, p value/c1
  float s2, s3;                   // pass B: c2,c3
  float rm;                       // JM mixed

#pragma unroll 1
  for (int ph = 0; ph < 2; ++ph) {  // two J3 passes share one code body
    J3 I[3], Opsi, Op;
    float d0 = ph ? kk  : a0;
    float d1 = ph ? b1s : a1;
    I[0].v = h0; I[0].c1 = d0;  I[0].c2 = 0.f; I[0].c3 = 0.f;
    I[1].v = h1; I[1].c1 = d1;  I[1].c2 = 0.f; I[1].c3 = 0.f;
    I[2].v = h2; I[2].c1 = 0.f; I[2].c2 = 0.f; I[2].c3 = 0.f;
    run_net<J3>(w, hb, hb1, hb2, hb3, I, Opsi, Op);
    if (ph == 0) {
      rc1 = Opsi.c1; rc2 = Opsi.c2; rc3 = Opsi.c3;
      rpv = Op.v;    rpc = Op.c1;
    } else {
      s2 = Opsi.c2; s3 = Opsi.c3;
    }
  }
  {
    JM I[3], Opsi, Op;
    I[0].v = h0; I[0].a = a0;  I[0].b = 0.f; I[0].m = 0.f;
    I[1].v = h1; I[1].a = a1;  I[1].b = 0.f; I[1].m = 0.f;
    I[2].v = h2; I[2].a = 0.f; I[2].b = kk;  I[2].m = 0.f;
    run_net<JM>(w, hb, hb1, hb2, hb3, I, Opsi, Op);
    rm = Opsi.m;   // psi_xt (q=0) / psi_yt (q=1)
  }

  // cross-family exchange (mask 4); every lane already has its own family
  float psi_y   = __shfl_xor(rc1, 4, 64);
  float psi_yy  = __shfl_xor(rc2, 4, 64);
  float psi_yyy = __shfl_xor(rc3, 4, 64);
  float p_y     = __shfl_xor(rpc, 4, 64);
  float S2m     = __shfl_xor(s2, 4, 64);
  float S3m     = __shfl_xor(s3, 4, 64);
  float psi_yt  = __shfl_xor(rm, 4, 64);

  if ((gid & 7) == 0) {
    float psi_x = rc1, psi_xx = rc2, psi_xxx = rc3;
    float p_val = rpv, p_x = rpc;
    float S2p = s2, S3p = s3;
    float psi_xt = rm;

    // polarization identities
    float psi_xy  = 0.25f * (S2p - S2m);
    float psi_xxy = (S3p - S3m - 2.0f * psi_yyy) * (1.0f / 6.0f);
    float psi_xyy = (S3p + S3m - 2.0f * psi_xxx) * (1.0f / 6.0f);

    float u = psi_y, vv = -psi_x;
    float u_x = psi_xy,  u_y = psi_yy,  u_t = psi_yt;
    float v_x = -psi_xx, v_y = -psi_xy, v_t = -psi_xt;
    float u_xx = psi_xxy,  u_yy = psi_yyy;
    float v_xx = -psi_xxx, v_yy = -psi_xyy;

    float lam1 = lam1p[0], lam2 = lam2p[0];
    float f_u = u_t + lam1 * (u * u_x + vv * u_y) + p_x - lam2 * (u_xx + u_yy);
    float f_v = v_t + lam1 * (u * v_x + vv * v_y) + p_y - lam2 * (v_xx + v_yy);

    out[pt] = u;
    out[NPTS + pt] = vv;
    out[2 * NPTS + pt] = p_val;
    out[3 * NPTS + pt] = f_u;
    out[4 * NPTS + pt] = f_v;
  }
}

extern "C" void kernel_launch(void* const* d_in, const int* in_sizes, int n_in,
                              void* d_out, int out_size, void* d_ws, size_t ws_size,
                              hipStream_t stream) {
  (void)in_sizes; (void)n_in; (void)out_size; (void)ws_size;
  const float* X = (const float*)d_in[0];
  const float* W[8]; const float* B[8];
  for (int i = 0; i < 8; ++i) {
    W[i] = (const float*)d_in[1 + 2 * i];
    B[i] = (const float*)d_in[2 + 2 * i];
  }
  const float* lam1 = (const float*)d_in[17];
  const float* lam2 = (const float*)d_in[18];
  unsigned* mm = (unsigned*)d_ws;
  float* out = (float*)d_out;

  hipLaunchKernelGGL(mm_reduce, dim3(MM_BLOCKS), dim3(256), 0, stream, X, mm);
  hipLaunchKernelGGL(pinn_main, dim3(8 * NPTS / 256), dim3(256), 0, stream,
                     X, W[0], B[0], W[1], B[1], W[2], B[2], W[3], B[3],
                     W[4], B[4], W[5], B[5], W[6], B[6], W[7], B[7],
                     lam1, lam2, mm, out);
}

// Round 10
// 221.812 us; speedup vs baseline: 1.2141x; 1.1239x over previous
//
#include <hip/hip_runtime.h>

#define NPTS 65536
#define MM_BLOCKS 64

// ---------------------------------------------------------------------------
// fast tanh: tanh(x) = 1 - 2/(e^{2x}+1). Saturates correctly at +-inf, no NaN.
// ---------------------------------------------------------------------------
__device__ __forceinline__ float fast_tanh(float x) {
  float e = __expf(2.0f * x);
  float r = __builtin_amdgcn_rcpf(e + 1.0f);
  return fmaf(-2.0f, r, 1.0f);
}

// ---------------------------------------------------------------------------
// Scalar jets (r6: packed fp32 is zero-gain on CDNA4 and halves ILP).
// J3  = 4-comp order-3 jet (pass 1, direction dA).
// J3t = 6-comp order-3 jet + t-leg (pass 2, direction dB = (k,+-k,0)):
//   t = d psi/dt, m = d2 psi / dB dt.  Through a=tanh(z):
//   r.t = f' t ; r.m = f'' c1 t + f' m  (JM recurrence on the shared chain).
//   m(+) = psi_xt + psi_yt (family q=0), m(-) = psi_xt - psi_yt (q=1)
//   -> psi_xt = (m+ + m-)/2, psi_yt = (m+ - m-)/2  [t-polarization]
// 6-comp is ONLY safe at quarter-split width: 6x5x2 = 60 buffer floats
// (r2's 6-comp at full width = 240 floats spilled 1.5 GB).
// ---------------------------------------------------------------------------
struct J3 {
  float v, c1, c2, c3;
  __device__ __forceinline__ static J3 seed(float bias) {
    J3 z; z.v = bias; z.c1 = 0.f; z.c2 = 0.f; z.c3 = 0.f; return z;
  }
  __device__ __forceinline__ void macc(float w, const J3& o) {
    v  = fmaf(w, o.v,  v);
    c1 = fmaf(w, o.c1, c1);
    c2 = fmaf(w, o.c2, c2);
    c3 = fmaf(w, o.c3, c3);
  }
  __device__ __forceinline__ J3 chain() const {
    float s    = fast_tanh(v);
    float fp   = fmaf(-s, s, 1.0f);             // 1 - s^2
    float fpp  = -2.0f * s * fp;                // -2 s (1-s^2)
    float fppp = fmaf(6.0f * s, s, -2.0f) * fp; // (6 s^2 - 2)(1 - s^2)
    J3 r;
    r.v  = s;
    r.c1 = fp * c1;
    r.c2 = fmaf(fpp, c1 * c1, fp * c2);
    r.c3 = fmaf(fppp * c1, c1 * c1, fmaf(3.0f * fpp, c1 * c2, fp * c3));
    return r;
  }
};

struct J3t {
  float v, c1, c2, c3, t, m;
  __device__ __forceinline__ static J3t seed(float bias) {
    J3t z; z.v = bias; z.c1 = 0.f; z.c2 = 0.f; z.c3 = 0.f; z.t = 0.f; z.m = 0.f;
    return z;
  }
  __device__ __forceinline__ void macc(float w, const J3t& o) {
    v  = fmaf(w, o.v,  v);
    c1 = fmaf(w, o.c1, c1);
    c2 = fmaf(w, o.c2, c2);
    c3 = fmaf(w, o.c3, c3);
    t  = fmaf(w, o.t,  t);
    m  = fmaf(w, o.m,  m);
  }
  __device__ __forceinline__ J3t chain() const {
    float s    = fast_tanh(v);
    float fp   = fmaf(-s, s, 1.0f);
    float fpp  = -2.0f * s * fp;
    float fppp = fmaf(6.0f * s, s, -2.0f) * fp;
    J3t r;
    r.v  = s;
    r.c1 = fp * c1;
    r.c2 = fmaf(fpp, c1 * c1, fp * c2);
    r.c3 = fmaf(fppp * c1, c1 * c1, fmaf(3.0f * fpp, c1 * c2, fp * c3));
    r.t  = fp * t;
    r.m  = fmaf(fpp, c1 * t, fp * m);
    return r;
  }
};

// lane exchange / butterfly-sum of a whole jet; masks 1/2/3 stay intra-quad
template <int M> __device__ __forceinline__ J3 shflx(const J3& o) {
  J3 r;
  r.v  = __shfl_xor(o.v,  M, 64);
  r.c1 = __shfl_xor(o.c1, M, 64);
  r.c2 = __shfl_xor(o.c2, M, 64);
  r.c3 = __shfl_xor(o.c3, M, 64);
  return r;
}
template <int M> __device__ __forceinline__ J3t shflx(const J3t& o) {
  J3t r;
  r.v  = __shfl_xor(o.v,  M, 64);
  r.c1 = __shfl_xor(o.c1, M, 64);
  r.c2 = __shfl_xor(o.c2, M, 64);
  r.c3 = __shfl_xor(o.c3, M, 64);
  r.t  = __shfl_xor(o.t,  M, 64);
  r.m  = __shfl_xor(o.m,  M, 64);
  return r;
}
template <int M> __device__ __forceinline__ void redsum(J3& z) {
  z.v  += __shfl_xor(z.v,  M, 64);
  z.c1 += __shfl_xor(z.c1, M, 64);
  z.c2 += __shfl_xor(z.c2, M, 64);
  z.c3 += __shfl_xor(z.c3, M, 64);
}
template <int M> __device__ __forceinline__ void redsum(J3t& z) {
  z.v  += __shfl_xor(z.v,  M, 64);
  z.c1 += __shfl_xor(z.c1, M, 64);
  z.c2 += __shfl_xor(z.c2, M, 64);
  z.c3 += __shfl_xor(z.c3, M, 64);
  z.t  += __shfl_xor(z.t,  M, 64);
  z.m  += __shfl_xor(z.m,  M, 64);
}

// ---------------------------------------------------------------------------
// Quarter-split 20->20 layer: this lane owns hidden units [hb, hb+5).
// Partner activations stream via intra-quad shfl_xor, ONE recv live at a time
// (liveness discipline -- r8's batched recvs overflowed the 128 cap).
// W row-major [i*20+j]; 4 base pointers, all other addressing immediate.
// ---------------------------------------------------------------------------
template <class J>
__device__ __forceinline__ void layer20_q(const float* __restrict__ W,
                                          const float* __restrict__ bias,
                                          int hb, int hb1, int hb2, int hb3,
                                          const J* A, J* B) {
  const float* B0 = W + hb  * 20 + hb;
  const float* B1 = W + hb1 * 20 + hb;
  const float* B2 = W + hb2 * 20 + hb;
  const float* B3 = W + hb3 * 20 + hb;
#pragma unroll
  for (int j = 0; j < 5; ++j) B[j] = J::seed(bias[hb + j]);
#pragma unroll
  for (int ii = 0; ii < 5; ++ii) {
    J s = A[ii];
#pragma unroll
    for (int j = 0; j < 5; ++j) B[j].macc(B0[ii * 20 + j], s);
    s = shflx<1>(A[ii]);
#pragma unroll
    for (int j = 0; j < 5; ++j) B[j].macc(B1[ii * 20 + j], s);
    s = shflx<2>(A[ii]);
#pragma unroll
    for (int j = 0; j < 5; ++j) B[j].macc(B2[ii * 20 + j], s);
    s = shflx<3>(A[ii]);
#pragma unroll
    for (int j = 0; j < 5; ++j) B[j].macc(B3[ii * 20 + j], s);
  }
#pragma unroll
  for (int j = 0; j < 5; ++j) B[j] = B[j].chain();
}

// LDS layout (floats, NATURAL row-major, straight copy):
// L1 W@0(9) b@9(3) | L2 W@12(60) b@72(20) | L3..L7 stride 420: W@92+420l(400)
// b@+400(20) | L8 W@2192(40) b@2232(2)
#define LDS_W_FLOATS 2234

// COPY-BACK mid loop (r0/r4/r5/r9 A/B: one unrolled body + B->A copy = zero
// spill; multiple unrolled 20x20 instances = GB-scale spill).  L8: per-lane
// partial dot over own 5 units, 2-stage intra-quad butterfly, bias added
// post-reduction, tanh chain.  WANTP=false skips the p-output partial.
template <class J, bool WANTP>
__device__ __forceinline__ void run_net(const float* __restrict__ w,
                                        int hb, int hb1, int hb2, int hb3,
                                        const J* in3, J& Opsi, J& Op) {
  J A[5], B[5];
  {
    J T[3];
#pragma unroll
    for (int j = 0; j < 3; ++j) {               // L1 3->3, duplicated
      J z = J::seed(w[9 + j]);
#pragma unroll
      for (int i = 0; i < 3; ++i) z.macc(w[i * 3 + j], in3[i]);
      T[j] = z.chain();
    }
#pragma unroll
    for (int j = 0; j < 5; ++j) {               // L2 3->20, split by quarter
      J z = J::seed(w[72 + hb + j]);
#pragma unroll
      for (int i = 0; i < 3; ++i) z.macc(w[12 + i * 20 + hb + j], T[i]);
      A[j] = z.chain();
    }
  }
#pragma unroll 1
  for (int l = 0; l < 5; ++l) {                 // L3..L7, one hot body
    const float* Wl = w + 92 + l * 420;
    layer20_q(Wl, Wl + 400, hb, hb1, hb2, hb3, A, B);
#pragma unroll
    for (int jj = 0; jj < 5; ++jj) A[jj] = B[jj];
  }
  J z0 = J::seed(0.f);                          // L8 psi partial
#pragma unroll
  for (int ii = 0; ii < 5; ++ii) z0.macc(w[2192 + (hb + ii) * 2 + 0], A[ii]);
  redsum<1>(z0); redsum<2>(z0);
  z0.v += w[2232];
  Opsi = z0.chain();
  if constexpr (WANTP) {
    J z1 = J::seed(0.f);                        // L8 p partial
#pragma unroll
    for (int ii = 0; ii < 5; ++ii) z1.macc(w[2192 + (hb + ii) * 2 + 1], A[ii]);
    redsum<1>(z1); redsum<2>(z1);
    z1.v += w[2233];
    Op = z1.chain();
  }
}

// ---------------------------------------------------------------------------
// min/max of X[:,0] via monotone-uint keys; one partial pair per block,
// butterfly-reduced per wave inside pinn_main.
// ---------------------------------------------------------------------------
__device__ __forceinline__ unsigned flipk(float f) {
  unsigned u = __float_as_uint(f);
  return (u & 0x80000000u) ? ~u : (u | 0x80000000u);
}
__device__ __forceinline__ float unflip(unsigned k) {
  unsigned u = (k & 0x80000000u) ? (k ^ 0x80000000u) : ~k;
  return __uint_as_float(u);
}

__global__ void __launch_bounds__(256) mm_reduce(const float* __restrict__ X,
                                                 unsigned* __restrict__ mm) {
  __shared__ unsigned smin[4], smax[4];
  unsigned kmin = 0xFFFFFFFFu, kmax = 0u;
  for (int i = blockIdx.x * 256 + threadIdx.x; i < NPTS; i += gridDim.x * 256) {
    unsigned key = flipk(X[3 * i]);
    kmin = min(kmin, key);
    kmax = max(kmax, key);
  }
#pragma unroll
  for (int o = 32; o > 0; o >>= 1) {
    kmin = min(kmin, (unsigned)__shfl_down((int)kmin, o, 64));
    kmax = max(kmax, (unsigned)__shfl_down((int)kmax, o, 64));
  }
  int wv = threadIdx.x >> 6;
  if ((threadIdx.x & 63) == 0) { smin[wv] = kmin; smax[wv] = kmax; }
  __syncthreads();
  if (threadIdx.x == 0) {
    kmin = min(min(smin[0], smin[1]), min(smin[2], smin[3]));
    kmax = max(max(smax[0], smax[1]), max(smax[2], smax[3]));
    mm[2 * blockIdx.x + 0] = kmin;
    mm[2 * blockIdx.x + 1] = kmax;
  }
}

// ---------------------------------------------------------------------------
// Main kernel: EIGHT LANES PER POINT, TWO passes (was three -- the JM pass is
// eliminated by the t-polarization identity, see J3t).  bits0-1 = hidden
// quarter Q, bit2 = family q.
//   pass 1, J3 along dA (x: q=0 / y: q=1): psi_x/xx/xxx (+p, p_x) | psi_y/...
//   pass 2, J3t along dB=(k,+-k,0) + t-leg: S2+-, S3+-, m+-
//   psi_xt = (m+ + m-)/2,  psi_yt = (m+ - m-)/2
// Per-weight comp-FMAs 12 -> 10, chains 3 -> 2, weight reads 3 -> 2 vs r9.
// Pass-2 buffers: 6 x 5 x 2 = 60 floats -> fits the 128-VGPR cap (r9's
// no-spill budget); (128,256] VGPR = 1 wave/SIMD (r5/r7), <=128 = 2 blocks/CU
// (r3/r9).  Copy-back mid loop mandatory (r0/r4 spill A/B).
// ---------------------------------------------------------------------------
__global__ void __launch_bounds__(256, 2) pinn_main(
    const float* __restrict__ X,
    const float* W1, const float* b1, const float* W2, const float* b2,
    const float* W3, const float* b3, const float* W4, const float* b4,
    const float* W5, const float* b5, const float* W6, const float* b6,
    const float* W7, const float* b7, const float* W8, const float* b8,
    const float* lam1p, const float* lam2p, const unsigned* __restrict__ mm,
    float* __restrict__ out) {
  __shared__ float w[LDS_W_FLOATS];
  {
    const float* Wsrc[8] = {W1, W2, W3, W4, W5, W6, W7, W8};
    const float* bsrc[8] = {b1, b2, b3, b4, b5, b6, b7, b8};
    const int nwA[8]  = {9, 60, 400, 400, 400, 400, 400, 40};
    const int nbA[8]  = {3, 20, 20, 20, 20, 20, 20, 2};
    const int offW[8] = {0, 12, 92, 512, 932, 1352, 1772, 2192};
    const int offB[8] = {9, 72, 492, 912, 1332, 1752, 2172, 2232};
#pragma unroll
    for (int a = 0; a < 8; ++a) {
      for (int s = threadIdx.x; s < nwA[a]; s += 256) w[offW[a] + s] = Wsrc[a][s];
      for (int s = threadIdx.x; s < nbA[a]; s += 256) w[offB[a] + s] = bsrc[a][s];
    }
  }

  const int lane = threadIdx.x & 63;
  const int gid  = blockIdx.x * 256 + threadIdx.x;
  const int pt   = gid >> 3;           // point index (eight lanes per point)
  const int Q    = gid & 3;            // hidden quarter
  const int q    = (gid >> 2) & 1;     // family
  const int hb   = 5 * Q;
  const int hb1  = 5 * (Q ^ 1);
  const int hb2  = 5 * (Q ^ 2);
  const int hb3  = 5 * (Q ^ 3);

  // global min/max: lane l holds block-partial l, butterfly across the wave
  unsigned pmin = mm[2 * lane + 0];
  unsigned pmax = mm[2 * lane + 1];
#pragma unroll
  for (int o = 1; o < 64; o <<= 1) {
    pmin = min(pmin, (unsigned)__shfl_xor((int)pmin, o, 64));
    pmax = max(pmax, (unsigned)__shfl_xor((int)pmax, o, 64));
  }
  float lb = unflip(pmin);
  float ub = unflip(pmax);
  float kk = 2.0f / (ub - lb);

  float x = X[3 * pt], y = X[3 * pt + 1], tt = X[3 * pt + 2];
  float h0 = fmaf(kk, x - lb, -1.0f);
  float h1 = fmaf(kk, y - lb, -1.0f);
  float h2 = fmaf(kk, tt - lb, -1.0f);

  __syncthreads();  // weights staged

  // family-selected seeds (cndmask, no branch)
  float a0 = q ? 0.0f : kk, a1 = q ? kk : 0.0f;   // pass 1: x-dir / y-dir
  float b1s = q ? -kk : kk;                        // pass 2: (k,+-k,0)

  float rc1, rc2, rc3, rpv, rpc;  // pass 1: psi jet, p value/deriv
  float s2, s3, rm;               // pass 2: S2, S3, m

  {
    J3 I[3], Opsi, Op;
    I[0].v = h0; I[0].c1 = a0;  I[0].c2 = 0.f; I[0].c3 = 0.f;
    I[1].v = h1; I[1].c1 = a1;  I[1].c2 = 0.f; I[1].c3 = 0.f;
    I[2].v = h2; I[2].c1 = 0.f; I[2].c2 = 0.f; I[2].c3 = 0.f;
    run_net<J3, true>(w, hb, hb1, hb2, hb3, I, Opsi, Op);
    rc1 = Opsi.c1; rc2 = Opsi.c2; rc3 = Opsi.c3;
    rpv = Op.v;    rpc = Op.c1;
  }
  {
    J3t I[3], Opsi, Odummy;
    I[0].v = h0; I[0].c1 = kk;  I[0].c2 = 0.f; I[0].c3 = 0.f; I[0].t = 0.f; I[0].m = 0.f;
    I[1].v = h1; I[1].c1 = b1s; I[1].c2 = 0.f; I[1].c3 = 0.f; I[1].t = 0.f; I[1].m = 0.f;
    I[2].v = h2; I[2].c1 = 0.f; I[2].c2 = 0.f; I[2].c3 = 0.f; I[2].t = kk;  I[2].m = 0.f;
    run_net<J3t, false>(w, hb, hb1, hb2, hb3, I, Opsi, Odummy);
    s2 = Opsi.c2; s3 = Opsi.c3; rm = Opsi.m;
  }

  // cross-family exchange (mask 4); every lane already holds its own family
  float psi_y   = __shfl_xor(rc1, 4, 64);
  float psi_yy  = __shfl_xor(rc2, 4, 64);
  float psi_yyy = __shfl_xor(rc3, 4, 64);
  float p_y     = __shfl_xor(rpc, 4, 64);
  float S2m     = __shfl_xor(s2, 4, 64);
  float S3m     = __shfl_xor(s3, 4, 64);
  float mB      = __shfl_xor(rm, 4, 64);   // m- (on q=0 lanes)

  if ((gid & 7) == 0) {
    float psi_x = rc1, psi_xx = rc2, psi_xxx = rc3;
    float p_val = rpv, p_x = rpc;
    float S2p = s2, S3p = s3;

    // polarization identities (spatial + NEW t-polarization)
    float psi_xy  = 0.25f * (S2p - S2m);
    float psi_xxy = (S3p - S3m - 2.0f * psi_yyy) * (1.0f / 6.0f);
    float psi_xyy = (S3p + S3m - 2.0f * psi_xxx) * (1.0f / 6.0f);
    float psi_xt  = 0.5f * (rm + mB);
    float psi_yt  = 0.5f * (rm - mB);

    float u = psi_y, vv = -psi_x;
    float u_x = psi_xy,  u_y = psi_yy,  u_t = psi_yt;
    float v_x = -psi_xx, v_y = -psi_xy, v_t = -psi_xt;
    float u_xx = psi_xxy,  u_yy = psi_yyy;
    float v_xx = -psi_xxx, v_yy = -psi_xyy;

    float lam1 = lam1p[0], lam2 = lam2p[0];
    float f_u = u_t + lam1 * (u * u_x + vv * u_y) + p_x - lam2 * (u_xx + u_yy);
    float f_v = v_t + lam1 * (u * v_x + vv * v_y) + p_y - lam2 * (v_xx + v_yy);

    out[pt] = u;
    out[NPTS + pt] = vv;
    out[2 * NPTS + pt] = p_val;
    out[3 * NPTS + pt] = f_u;
    out[4 * NPTS + pt] = f_v;
  }
}

extern "C" void kernel_launch(void* const* d_in, const int* in_sizes, int n_in,
                              void* d_out, int out_size, void* d_ws, size_t ws_size,
                              hipStream_t stream) {
  (void)in_sizes; (void)n_in; (void)out_size; (void)ws_size;
  const float* X = (const float*)d_in[0];
  const float* W[8]; const float* B[8];
  for (int i = 0; i < 8; ++i) {
    W[i] = (const float*)d_in[1 + 2 * i];
    B[i] = (const float*)d_in[2 + 2 * i];
  }
  const float* lam1 = (const float*)d_in[17];
  const float* lam2 = (const float*)d_in[18];
  unsigned* mm = (unsigned*)d_ws;
  float* out = (float*)d_out;

  hipLaunchKernelGGL(mm_reduce, dim3(MM_BLOCKS), dim3(256), 0, stream, X, mm);
  hipLaunchKernelGGL(pinn_main, dim3(8 * NPTS / 256), dim3(256), 0, stream,
                     X, W[0], B[0], W[1], B[1], W[2], B[2], W[3], B[3],
                     W[4], B[4], W[5], B[5], W[6], B[6], W[7], B[7],
                     lam1, lam2, mm, out);
}

// Round 11
// 205.447 us; speedup vs baseline: 1.3108x; 1.0797x over previous
//
#include <hip/hip_runtime.h>

#define NPTS 65536
#define MM_BLOCKS 64

// ---------------------------------------------------------------------------
// fast tanh: tanh(x) = 1 - 2/(e^{2x}+1). Saturates correctly at +-inf, no NaN.
// ---------------------------------------------------------------------------
__device__ __forceinline__ float fast_tanh(float x) {
  float e = __expf(2.0f * x);
  float r = __builtin_amdgcn_rcpf(e + 1.0f);
  return fmaf(-2.0f, r, 1.0f);
}

// ---------------------------------------------------------------------------
// DPP quad_perm lane exchange for xor masks 1/2/3 (intra-quad -- this is why
// the hidden-quarter index Q lives in lane bits 0-1).  __shfl_xor lowers to
// ds_bpermute_b32 (LDS pipe, ~30-60cy + lgkmcnt, contends with weight
// ds_reads); v_mov_b32 dpp quad_perm is a 1-op VALU swap with forwarding.
//   xor1 -> [1,0,3,2] = 0xB1, xor2 -> [2,3,0,1] = 0x4E, xor3 -> [3,2,1,0] = 0x1B
// ---------------------------------------------------------------------------
template <int M> __device__ __forceinline__ constexpr int qpctrl() {
  return M == 1 ? 0xB1 : (M == 2 ? 0x4E : 0x1B);
}
template <int M> __device__ __forceinline__ float qperm(float x) {
  return __int_as_float(__builtin_amdgcn_mov_dpp(
      __float_as_int(x), qpctrl<M>(), 0xF, 0xF, true));
}

// ---------------------------------------------------------------------------
// Scalar jets (r6: packed fp32 is zero-gain on CDNA4 and halves ILP).
// J3  = 4-comp order-3 jet (pass 1, direction dA).
// J3t = 6-comp order-3 jet + t-leg (pass 2, direction dB = (k,+-k,0)):
//   m(+-) = psi_xt +- psi_yt -> psi_xt = (m+ + m-)/2, psi_yt = (m+ - m-)/2.
// 6-comp is ONLY safe at quarter-split width (60 buffer floats; r2's
// full-width 6-comp = 240 floats spilled 1.5 GB).
// ---------------------------------------------------------------------------
struct J3 {
  float v, c1, c2, c3;
  __device__ __forceinline__ static J3 seed(float bias) {
    J3 z; z.v = bias; z.c1 = 0.f; z.c2 = 0.f; z.c3 = 0.f; return z;
  }
  __device__ __forceinline__ void macc(float w, const J3& o) {
    v  = fmaf(w, o.v,  v);
    c1 = fmaf(w, o.c1, c1);
    c2 = fmaf(w, o.c2, c2);
    c3 = fmaf(w, o.c3, c3);
  }
  __device__ __forceinline__ J3 chain() const {
    float s    = fast_tanh(v);
    float fp   = fmaf(-s, s, 1.0f);             // 1 - s^2
    float fpp  = -2.0f * s * fp;                // -2 s (1-s^2)
    float fppp = fmaf(6.0f * s, s, -2.0f) * fp; // (6 s^2 - 2)(1 - s^2)
    J3 r;
    r.v  = s;
    r.c1 = fp * c1;
    r.c2 = fmaf(fpp, c1 * c1, fp * c2);
    r.c3 = fmaf(fppp * c1, c1 * c1, fmaf(3.0f * fpp, c1 * c2, fp * c3));
    return r;
  }
};

struct J3t {
  float v, c1, c2, c3, t, m;
  __device__ __forceinline__ static J3t seed(float bias) {
    J3t z; z.v = bias; z.c1 = 0.f; z.c2 = 0.f; z.c3 = 0.f; z.t = 0.f; z.m = 0.f;
    return z;
  }
  __device__ __forceinline__ void macc(float w, const J3t& o) {
    v  = fmaf(w, o.v,  v);
    c1 = fmaf(w, o.c1, c1);
    c2 = fmaf(w, o.c2, c2);
    c3 = fmaf(w, o.c3, c3);
    t  = fmaf(w, o.t,  t);
    m  = fmaf(w, o.m,  m);
  }
  __device__ __forceinline__ J3t chain() const {
    float s    = fast_tanh(v);
    float fp   = fmaf(-s, s, 1.0f);
    float fpp  = -2.0f * s * fp;
    float fppp = fmaf(6.0f * s, s, -2.0f) * fp;
    J3t r;
    r.v  = s;
    r.c1 = fp * c1;
    r.c2 = fmaf(fpp, c1 * c1, fp * c2);
    r.c3 = fmaf(fppp * c1, c1 * c1, fmaf(3.0f * fpp, c1 * c2, fp * c3));
    r.t  = fp * t;
    r.m  = fmaf(fpp, c1 * t, fp * m);
    return r;
  }
};

// whole-jet DPP exchange / butterfly-sum (hot path, masks 1/2/3 only)
template <int M> __device__ __forceinline__ J3 shflx(const J3& o) {
  J3 r;
  r.v  = qperm<M>(o.v);
  r.c1 = qperm<M>(o.c1);
  r.c2 = qperm<M>(o.c2);
  r.c3 = qperm<M>(o.c3);
  return r;
}
template <int M> __device__ __forceinline__ J3t shflx(const J3t& o) {
  J3t r;
  r.v  = qperm<M>(o.v);
  r.c1 = qperm<M>(o.c1);
  r.c2 = qperm<M>(o.c2);
  r.c3 = qperm<M>(o.c3);
  r.t  = qperm<M>(o.t);
  r.m  = qperm<M>(o.m);
  return r;
}
template <int M> __device__ __forceinline__ void redsum(J3& z) {
  z.v  += qperm<M>(z.v);
  z.c1 += qperm<M>(z.c1);
  z.c2 += qperm<M>(z.c2);
  z.c3 += qperm<M>(z.c3);
}
template <int M> __device__ __forceinline__ void redsum(J3t& z) {
  z.v  += qperm<M>(z.v);
  z.c1 += qperm<M>(z.c1);
  z.c2 += qperm<M>(z.c2);
  z.c3 += qperm<M>(z.c3);
  z.t  += qperm<M>(z.t);
  z.m  += qperm<M>(z.m);
}

// ---------------------------------------------------------------------------
// Quarter-split 20->20 layer: this lane owns hidden units [hb, hb+5).
// Partner activations arrive via DPP quad_perm, ONE recv live at a time
// (liveness discipline -- r8's batched recvs overflowed the 128 cap).
// W row-major [i*20+j]; 4 base pointers, all other addressing immediate.
// ---------------------------------------------------------------------------
template <class J>
__device__ __forceinline__ void layer20_q(const float* __restrict__ W,
                                          const float* __restrict__ bias,
                                          int hb, int hb1, int hb2, int hb3,
                                          const J* A, J* B) {
  const float* B0 = W + hb  * 20 + hb;
  const float* B1 = W + hb1 * 20 + hb;
  const float* B2 = W + hb2 * 20 + hb;
  const float* B3 = W + hb3 * 20 + hb;
#pragma unroll
  for (int j = 0; j < 5; ++j) B[j] = J::seed(bias[hb + j]);
#pragma unroll
  for (int ii = 0; ii < 5; ++ii) {
    J s = A[ii];
#pragma unroll
    for (int j = 0; j < 5; ++j) B[j].macc(B0[ii * 20 + j], s);
    s = shflx<1>(A[ii]);
#pragma unroll
    for (int j = 0; j < 5; ++j) B[j].macc(B1[ii * 20 + j], s);
    s = shflx<2>(A[ii]);
#pragma unroll
    for (int j = 0; j < 5; ++j) B[j].macc(B2[ii * 20 + j], s);
    s = shflx<3>(A[ii]);
#pragma unroll
    for (int j = 0; j < 5; ++j) B[j].macc(B3[ii * 20 + j], s);
  }
#pragma unroll
  for (int j = 0; j < 5; ++j) B[j] = B[j].chain();
}

// LDS layout (floats, NATURAL row-major, straight copy):
// L1 W@0(9) b@9(3) | L2 W@12(60) b@72(20) | L3..L7 stride 420: W@92+420l(400)
// b@+400(20) | L8 W@2192(40) b@2232(2)
#define LDS_W_FLOATS 2234

// COPY-BACK mid loop (r0/r4/r5/r9 A/B: one unrolled body + B->A copy = zero
// spill; multiple unrolled 20x20 instances = GB-scale spill).  L8: per-lane
// partial dot over own 5 units, 2-stage intra-quad DPP butterfly, bias added
// post-reduction, tanh chain.  WANTP=false skips the p-output partial.
template <class J, bool WANTP>
__device__ __forceinline__ void run_net(const float* __restrict__ w,
                                        int hb, int hb1, int hb2, int hb3,
                                        const J* in3, J& Opsi, J& Op) {
  J A[5], B[5];
  {
    J T[3];
#pragma unroll
    for (int j = 0; j < 3; ++j) {               // L1 3->3, duplicated
      J z = J::seed(w[9 + j]);
#pragma unroll
      for (int i = 0; i < 3; ++i) z.macc(w[i * 3 + j], in3[i]);
      T[j] = z.chain();
    }
#pragma unroll
    for (int j = 0; j < 5; ++j) {               // L2 3->20, split by quarter
      J z = J::seed(w[72 + hb + j]);
#pragma unroll
      for (int i = 0; i < 3; ++i) z.macc(w[12 + i * 20 + hb + j], T[i]);
      A[j] = z.chain();
    }
  }
#pragma unroll 1
  for (int l = 0; l < 5; ++l) {                 // L3..L7, one hot body
    const float* Wl = w + 92 + l * 420;
    layer20_q(Wl, Wl + 400, hb, hb1, hb2, hb3, A, B);
#pragma unroll
    for (int jj = 0; jj < 5; ++jj) A[jj] = B[jj];
  }
  J z0 = J::seed(0.f);                          // L8 psi partial
#pragma unroll
  for (int ii = 0; ii < 5; ++ii) z0.macc(w[2192 + (hb + ii) * 2 + 0], A[ii]);
  redsum<1>(z0); redsum<2>(z0);
  z0.v += w[2232];
  Opsi = z0.chain();
  if constexpr (WANTP) {
    J z1 = J::seed(0.f);                        // L8 p partial
#pragma unroll
    for (int ii = 0; ii < 5; ++ii) z1.macc(w[2192 + (hb + ii) * 2 + 1], A[ii]);
    redsum<1>(z1); redsum<2>(z1);
    z1.v += w[2233];
    Op = z1.chain();
  }
}

// ---------------------------------------------------------------------------
// min/max of X[:,0] via monotone-uint keys; one partial pair per block,
// butterfly-reduced per wave inside pinn_main.
// ---------------------------------------------------------------------------
__device__ __forceinline__ unsigned flipk(float f) {
  unsigned u = __float_as_uint(f);
  return (u & 0x80000000u) ? ~u : (u | 0x80000000u);
}
__device__ __forceinline__ float unflip(unsigned k) {
  unsigned u = (k & 0x80000000u) ? (k ^ 0x80000000u) : ~k;
  return __uint_as_float(u);
}

__global__ void __launch_bounds__(256) mm_reduce(const float* __restrict__ X,
                                                 unsigned* __restrict__ mm) {
  __shared__ unsigned smin[4], smax[4];
  unsigned kmin = 0xFFFFFFFFu, kmax = 0u;
  for (int i = blockIdx.x * 256 + threadIdx.x; i < NPTS; i += gridDim.x * 256) {
    unsigned key = flipk(X[3 * i]);
    kmin = min(kmin, key);
    kmax = max(kmax, key);
  }
#pragma unroll
  for (int o = 32; o > 0; o >>= 1) {
    kmin = min(kmin, (unsigned)__shfl_down((int)kmin, o, 64));
    kmax = max(kmax, (unsigned)__shfl_down((int)kmax, o, 64));
  }
  int wv = threadIdx.x >> 6;
  if ((threadIdx.x & 63) == 0) { smin[wv] = kmin; smax[wv] = kmax; }
  __syncthreads();
  if (threadIdx.x == 0) {
    kmin = min(min(smin[0], smin[1]), min(smin[2], smin[3]));
    kmax = max(max(smax[0], smax[1]), max(smax[2], smax[3]));
    mm[2 * blockIdx.x + 0] = kmin;
    mm[2 * blockIdx.x + 1] = kmax;
  }
}

// ---------------------------------------------------------------------------
// Main kernel: EIGHT LANES PER POINT, TWO passes (r10 structure, unchanged
// except hot shuffles -> DPP).  bits0-1 = hidden quarter Q, bit2 = family q.
//   pass 1, J3 along dA (x: q=0 / y: q=1): psi_x/xx/xxx (+p, p_x) | psi_y/...
//   pass 2, J3t along dB=(k,+-k,0) + t-leg: S2+-, S3+-, m+-
//   psi_xt = (m+ + m-)/2,  psi_yt = (m+ - m-)/2   [t-polarization]
// Residency (measured r3/r5/r7/r9): VGPR (128,256] -> 1 wave/SIMD; ==128
// via __launch_bounds__(256,2) -> 2 blocks/CU.  Copy-back mid loop mandatory.
// ---------------------------------------------------------------------------
__global__ void __launch_bounds__(256, 2) pinn_main(
    const float* __restrict__ X,
    const float* W1, const float* b1, const float* W2, const float* b2,
    const float* W3, const float* b3, const float* W4, const float* b4,
    const float* W5, const float* b5, const float* W6, const float* b6,
    const float* W7, const float* b7, const float* W8, const float* b8,
    const float* lam1p, const float* lam2p, const unsigned* __restrict__ mm,
    float* __restrict__ out) {
  __shared__ float w[LDS_W_FLOATS];
  {
    const float* Wsrc[8] = {W1, W2, W3, W4, W5, W6, W7, W8};
    const float* bsrc[8] = {b1, b2, b3, b4, b5, b6, b7, b8};
    const int nwA[8]  = {9, 60, 400, 400, 400, 400, 400, 40};
    const int nbA[8]  = {3, 20, 20, 20, 20, 20, 20, 2};
    const int offW[8] = {0, 12, 92, 512, 932, 1352, 1772, 2192};
    const int offB[8] = {9, 72, 492, 912, 1332, 1752, 2172, 2232};
#pragma unroll
    for (int a = 0; a < 8; ++a) {
      for (int s = threadIdx.x; s < nwA[a]; s += 256) w[offW[a] + s] = Wsrc[a][s];
      for (int s = threadIdx.x; s < nbA[a]; s += 256) w[offB[a] + s] = bsrc[a][s];
    }
  }

  const int lane = threadIdx.x & 63;
  const int gid  = blockIdx.x * 256 + threadIdx.x;
  const int pt   = gid >> 3;           // point index (eight lanes per point)
  const int Q    = gid & 3;            // hidden quarter
  const int q    = (gid >> 2) & 1;     // family
  const int hb   = 5 * Q;
  const int hb1  = 5 * (Q ^ 1);
  const int hb2  = 5 * (Q ^ 2);
  const int hb3  = 5 * (Q ^ 3);

  // global min/max: lane l holds block-partial l, butterfly across the wave
  unsigned pmin = mm[2 * lane + 0];
  unsigned pmax = mm[2 * lane + 1];
#pragma unroll
  for (int o = 1; o < 64; o <<= 1) {
    pmin = min(pmin, (unsigned)__shfl_xor((int)pmin, o, 64));
    pmax = max(pmax, (unsigned)__shfl_xor((int)pmax, o, 64));
  }
  float lb = unflip(pmin);
  float ub = unflip(pmax);
  float kk = 2.0f / (ub - lb);

  float x = X[3 * pt], y = X[3 * pt + 1], tt = X[3 * pt + 2];
  float h0 = fmaf(kk, x - lb, -1.0f);
  float h1 = fmaf(kk, y - lb, -1.0f);
  float h2 = fmaf(kk, tt - lb, -1.0f);

  __syncthreads();  // weights staged

  // family-selected seeds (cndmask, no branch)
  float a0 = q ? 0.0f : kk, a1 = q ? kk : 0.0f;   // pass 1: x-dir / y-dir
  float b1s = q ? -kk : kk;                        // pass 2: (k,+-k,0)

  float rc1, rc2, rc3, rpv, rpc;  // pass 1: psi jet, p value/deriv
  float s2, s3, rm;               // pass 2: S2, S3, m

  {
    J3 I[3], Opsi, Op;
    I[0].v = h0; I[0].c1 = a0;  I[0].c2 = 0.f; I[0].c3 = 0.f;
    I[1].v = h1; I[1].c1 = a1;  I[1].c2 = 0.f; I[1].c3 = 0.f;
    I[2].v = h2; I[2].c1 = 0.f; I[2].c2 = 0.f; I[2].c3 = 0.f;
    run_net<J3, true>(w, hb, hb1, hb2, hb3, I, Opsi, Op);
    rc1 = Opsi.c1; rc2 = Opsi.c2; rc3 = Opsi.c3;
    rpv = Op.v;    rpc = Op.c1;
  }
  {
    J3t I[3], Opsi, Odummy;
    I[0].v = h0; I[0].c1 = kk;  I[0].c2 = 0.f; I[0].c3 = 0.f; I[0].t = 0.f; I[0].m = 0.f;
    I[1].v = h1; I[1].c1 = b1s; I[1].c2 = 0.f; I[1].c3 = 0.f; I[1].t = 0.f; I[1].m = 0.f;
    I[2].v = h2; I[2].c1 = 0.f; I[2].c2 = 0.f; I[2].c3 = 0.f; I[2].t = kk;  I[2].m = 0.f;
    run_net<J3t, false>(w, hb, hb1, hb2, hb3, I, Opsi, Odummy);
    s2 = Opsi.c2; s3 = Opsi.c3; rm = Opsi.m;
  }

  // cross-family exchange (mask 4 -- crosses quads, keep __shfl_xor; cold)
  float psi_y   = __shfl_xor(rc1, 4, 64);
  float psi_yy  = __shfl_xor(rc2, 4, 64);
  float psi_yyy = __shfl_xor(rc3, 4, 64);
  float p_y     = __shfl_xor(rpc, 4, 64);
  float S2m     = __shfl_xor(s2, 4, 64);
  float S3m     = __shfl_xor(s3, 4, 64);
  float mB      = __shfl_xor(rm, 4, 64);   // m- (on q=0 lanes)

  if ((gid & 7) == 0) {
    float psi_x = rc1, psi_xx = rc2, psi_xxx = rc3;
    float p_val = rpv, p_x = rpc;
    float S2p = s2, S3p = s3;

    // polarization identities (spatial + t-polarization)
    float psi_xy  = 0.25f * (S2p - S2m);
    float psi_xxy = (S3p - S3m - 2.0f * psi_yyy) * (1.0f / 6.0f);
    float psi_xyy = (S3p + S3m - 2.0f * psi_xxx) * (1.0f / 6.0f);
    float psi_xt  = 0.5f * (rm + mB);
    float psi_yt  = 0.5f * (rm - mB);

    float u = psi_y, vv = -psi_x;
    float u_x = psi_xy,  u_y = psi_yy,  u_t = psi_yt;
    float v_x = -psi_xx, v_y = -psi_xy, v_t = -psi_xt;
    float u_xx = psi_xxy,  u_yy = psi_yyy;
    float v_xx = -psi_xxx, v_yy = -psi_xyy;

    float lam1 = lam1p[0], lam2 = lam2p[0];
    float f_u = u_t + lam1 * (u * u_x + vv * u_y) + p_x - lam2 * (u_xx + u_yy);
    float f_v = v_t + lam1 * (u * v_x + vv * v_y) + p_y - lam2 * (v_xx + v_yy);

    out[pt] = u;
    out[NPTS + pt] = vv;
    out[2 * NPTS + pt] = p_val;
    out[3 * NPTS + pt] = f_u;
    out[4 * NPTS + pt] = f_v;
  }
}

extern "C" void kernel_launch(void* const* d_in, const int* in_sizes, int n_in,
                              void* d_out, int out_size, void* d_ws, size_t ws_size,
                              hipStream_t stream) {
  (void)in_sizes; (void)n_in; (void)out_size; (void)ws_size;
  const float* X = (const float*)d_in[0];
  const float* W[8]; const float* B[8];
  for (int i = 0; i < 8; ++i) {
    W[i] = (const float*)d_in[1 + 2 * i];
    B[i] = (const float*)d_in[2 + 2 * i];
  }
  const float* lam1 = (const float*)d_in[17];
  const float* lam2 = (const float*)d_in[18];
  unsigned* mm = (unsigned*)d_ws;
  float* out = (float*)d_out;

  hipLaunchKernelGGL(mm_reduce, dim3(MM_BLOCKS), dim3(256), 0, stream, X, mm);
  hipLaunchKernelGGL(pinn_main, dim3(8 * NPTS / 256), dim3(256), 0, stream,
                     X, W[0], B[0], W[1], B[1], W[2], B[2], W[3], B[3],
                     W[4], B[4], W[5], B[5], W[6], B[6], W[7], B[7],
                     lam1, lam2, mm, out);
}

// Round 12
// 181.746 us; speedup vs baseline: 1.4817x; 1.1304x over previous
//
#include <hip/hip_runtime.h>

#define NPTS 65536
#define MM_BLOCKS 64

// ---------------------------------------------------------------------------
// fast tanh: tanh(x) = 1 - 2/(e^{2x}+1). Saturates correctly at +-inf, no NaN.
// ---------------------------------------------------------------------------
__device__ __forceinline__ float fast_tanh(float x) {
  float e = __expf(2.0f * x);
  float r = __builtin_amdgcn_rcpf(e + 1.0f);
  return fmaf(-2.0f, r, 1.0f);
}

// ---------------------------------------------------------------------------
// DPP quad_perm lane exchange for xor masks 1/2/3 (intra-quad -- Q lives in
// lane bits 0-1).  1-op VALU swap with forwarding; no LDS pipe, no lgkmcnt
// (r11: converting shuffles ds_bpermute -> DPP was 149.8 -> 130.8 us).
// ---------------------------------------------------------------------------
template <int M> __device__ __forceinline__ constexpr int qpctrl() {
  return M == 1 ? 0xB1 : (M == 2 ? 0x4E : 0x1B);
}
template <int M> __device__ __forceinline__ float qperm(float x) {
  return __int_as_float(__builtin_amdgcn_mov_dpp(
      __float_as_int(x), qpctrl<M>(), 0xF, 0xF, true));
}

// ---------------------------------------------------------------------------
// FUSED 9-component jet: ONE network pass computes everything (r10/r11 used
// two passes that walked the same value chain and read the same weights
// twice -- this halves LDS weight reads and shares the tanh chain).
//   v            value
//   a1,a2,a3     order-3 jet along dA  (x-dir for q=0, y-dir for q=1)
//   b1,b2,b3     order-3 jet along dB = (k,+-k,0)
//   t, m         t-leg: t = d psi/dt, m = d2 psi / dB dt
// Through a=tanh(z), with s=tanh, fp=1-s^2, fpp=-2 s fp, fppp=(6s^2-2)fp:
//   each leg follows its own standard recurrence on the SHARED chain.
// Outputs are bit-identical to the r11 two-pass version.
// t-polarization: m(+-) = psi_xt +- psi_yt -> psi_xt = (m+ + m-)/2, etc.
// Buffers: 9 x 5 x 2 = 90 floats; r11 measured misc overhead ~13 regs ->
// ~120 total, fits the 128 cap (vs r8's knife-edge failure: no persistent
// cross-pass scalars here, ONE recv live at a time).
// ---------------------------------------------------------------------------
struct J9 {
  float v, a1, a2, a3, b1, b2, b3, t, m;
  __device__ __forceinline__ static J9 seed(float bias) {
    J9 z; z.v = bias;
    z.a1 = 0.f; z.a2 = 0.f; z.a3 = 0.f;
    z.b1 = 0.f; z.b2 = 0.f; z.b3 = 0.f;
    z.t = 0.f; z.m = 0.f;
    return z;
  }
  __device__ __forceinline__ void macc(float w, const J9& o) {
    v  = fmaf(w, o.v,  v);
    a1 = fmaf(w, o.a1, a1);
    a2 = fmaf(w, o.a2, a2);
    a3 = fmaf(w, o.a3, a3);
    b1 = fmaf(w, o.b1, b1);
    b2 = fmaf(w, o.b2, b2);
    b3 = fmaf(w, o.b3, b3);
    t  = fmaf(w, o.t,  t);
    m  = fmaf(w, o.m,  m);
  }
  __device__ __forceinline__ J9 chain() const {
    float s    = fast_tanh(v);
    float fp   = fmaf(-s, s, 1.0f);             // 1 - s^2
    float fpp  = -2.0f * s * fp;                // -2 s (1-s^2)
    float fppp = fmaf(6.0f * s, s, -2.0f) * fp; // (6 s^2 - 2)(1 - s^2)
    J9 r;
    r.v  = s;
    r.a1 = fp * a1;
    r.a2 = fmaf(fpp, a1 * a1, fp * a2);
    r.a3 = fmaf(fppp * a1, a1 * a1, fmaf(3.0f * fpp, a1 * a2, fp * a3));
    r.b1 = fp * b1;
    r.b2 = fmaf(fpp, b1 * b1, fp * b2);
    r.b3 = fmaf(fppp * b1, b1 * b1, fmaf(3.0f * fpp, b1 * b2, fp * b3));
    r.t  = fp * t;
    r.m  = fmaf(fpp, b1 * t, fp * m);
    return r;
  }
};

// whole-jet DPP exchange / butterfly-sum (hot path, masks 1/2/3 only)
template <int M> __device__ __forceinline__ J9 shflx(const J9& o) {
  J9 r;
  r.v  = qperm<M>(o.v);
  r.a1 = qperm<M>(o.a1);
  r.a2 = qperm<M>(o.a2);
  r.a3 = qperm<M>(o.a3);
  r.b1 = qperm<M>(o.b1);
  r.b2 = qperm<M>(o.b2);
  r.b3 = qperm<M>(o.b3);
  r.t  = qperm<M>(o.t);
  r.m  = qperm<M>(o.m);
  return r;
}
template <int M> __device__ __forceinline__ void redsum(J9& z) {
  z.v  += qperm<M>(z.v);
  z.a1 += qperm<M>(z.a1);
  z.a2 += qperm<M>(z.a2);
  z.a3 += qperm<M>(z.a3);
  z.b1 += qperm<M>(z.b1);
  z.b2 += qperm<M>(z.b2);
  z.b3 += qperm<M>(z.b3);
  z.t  += qperm<M>(z.t);
  z.m  += qperm<M>(z.m);
}

// ---------------------------------------------------------------------------
// Quarter-split 20->20 layer: this lane owns hidden units [hb, hb+5).
// Partner activations via DPP quad_perm, ONE recv live at a time (liveness
// discipline -- r8's batched recvs overflowed the 128 cap).
// W row-major [i*20+j]; 4 base pointers, all other addressing immediate.
// ---------------------------------------------------------------------------
__device__ __forceinline__ void layer20_q(const float* __restrict__ W,
                                          const float* __restrict__ bias,
                                          int hb, int hb1, int hb2, int hb3,
                                          const J9* A, J9* B) {
  const float* B0 = W + hb  * 20 + hb;
  const float* B1 = W + hb1 * 20 + hb;
  const float* B2 = W + hb2 * 20 + hb;
  const float* B3 = W + hb3 * 20 + hb;
#pragma unroll
  for (int j = 0; j < 5; ++j) B[j] = J9::seed(bias[hb + j]);
#pragma unroll
  for (int ii = 0; ii < 5; ++ii) {
    J9 s = A[ii];
#pragma unroll
    for (int j = 0; j < 5; ++j) B[j].macc(B0[ii * 20 + j], s);
    s = shflx<1>(A[ii]);
#pragma unroll
    for (int j = 0; j < 5; ++j) B[j].macc(B1[ii * 20 + j], s);
    s = shflx<2>(A[ii]);
#pragma unroll
    for (int j = 0; j < 5; ++j) B[j].macc(B2[ii * 20 + j], s);
    s = shflx<3>(A[ii]);
#pragma unroll
    for (int j = 0; j < 5; ++j) B[j].macc(B3[ii * 20 + j], s);
  }
#pragma unroll
  for (int j = 0; j < 5; ++j) B[j] = B[j].chain();
}

// LDS layout (floats, NATURAL row-major, straight copy):
// L1 W@0(9) b@9(3) | L2 W@12(60) b@72(20) | L3..L7 stride 420: W@92+420l(400)
// b@+400(20) | L8 W@2192(40) b@2232(2)
#define LDS_W_FLOATS 2234

// ---------------------------------------------------------------------------
// min/max of X[:,0] via monotone-uint keys; one partial pair per block,
// butterfly-reduced per wave inside pinn_main.
// ---------------------------------------------------------------------------
__device__ __forceinline__ unsigned flipk(float f) {
  unsigned u = __float_as_uint(f);
  return (u & 0x80000000u) ? ~u : (u | 0x80000000u);
}
__device__ __forceinline__ float unflip(unsigned k) {
  unsigned u = (k & 0x80000000u) ? (k ^ 0x80000000u) : ~k;
  return __uint_as_float(u);
}

__global__ void __launch_bounds__(256) mm_reduce(const float* __restrict__ X,
                                                 unsigned* __restrict__ mm) {
  __shared__ unsigned smin[4], smax[4];
  unsigned kmin = 0xFFFFFFFFu, kmax = 0u;
  for (int i = blockIdx.x * 256 + threadIdx.x; i < NPTS; i += gridDim.x * 256) {
    unsigned key = flipk(X[3 * i]);
    kmin = min(kmin, key);
    kmax = max(kmax, key);
  }
#pragma unroll
  for (int o = 32; o > 0; o >>= 1) {
    kmin = min(kmin, (unsigned)__shfl_down((int)kmin, o, 64));
    kmax = max(kmax, (unsigned)__shfl_down((int)kmax, o, 64));
  }
  int wv = threadIdx.x >> 6;
  if ((threadIdx.x & 63) == 0) { smin[wv] = kmin; smax[wv] = kmax; }
  __syncthreads();
  if (threadIdx.x == 0) {
    kmin = min(min(smin[0], smin[1]), min(smin[2], smin[3]));
    kmax = max(max(smax[0], smax[1]), max(smax[2], smax[3]));
    mm[2 * blockIdx.x + 0] = kmin;
    mm[2 * blockIdx.x + 1] = kmax;
  }
}

// ---------------------------------------------------------------------------
// Main kernel: EIGHT LANES PER POINT, ONE fused pass (was two in r10/r11).
// bits0-1 = hidden quarter Q, bit2 = family q.
//   q=0: dA=(k,0,0), dB=(k, k,0):  psi_x/xx/xxx, S2+/S3+, m+, p, p_x
//   q=1: dA=(0,k,0), dB=(k,-k,0):  psi_y/yy/yyy, S2-/S3-, m-, p_y
//   psi_xt = (m+ + m-)/2,  psi_yt = (m+ - m-)/2   [t-polarization]
// p output only needs {v, a1}: 2-float partial, not a full J9.
// Residency (measured r3/r5/r7/r9): VGPR (128,256] -> 1 wave/SIMD; <=128 via
// __launch_bounds__(256,2) -> 2 blocks/CU.  Copy-back mid loop mandatory
// (r0/r4 A/B: unrolled ping-pong = GB-scale spill).
// ---------------------------------------------------------------------------
__global__ void __launch_bounds__(256, 2) pinn_main(
    const float* __restrict__ X,
    const float* W1, const float* b1, const float* W2, const float* b2,
    const float* W3, const float* b3, const float* W4, const float* b4,
    const float* W5, const float* b5, const float* W6, const float* b6,
    const float* W7, const float* b7, const float* W8, const float* b8,
    const float* lam1p, const float* lam2p, const unsigned* __restrict__ mm,
    float* __restrict__ out) {
  __shared__ float w[LDS_W_FLOATS];
  {
    const float* Wsrc[8] = {W1, W2, W3, W4, W5, W6, W7, W8};
    const float* bsrc[8] = {b1, b2, b3, b4, b5, b6, b7, b8};
    const int nwA[8]  = {9, 60, 400, 400, 400, 400, 400, 40};
    const int nbA[8]  = {3, 20, 20, 20, 20, 20, 20, 2};
    const int offW[8] = {0, 12, 92, 512, 932, 1352, 1772, 2192};
    const int offB[8] = {9, 72, 492, 912, 1332, 1752, 2172, 2232};
#pragma unroll
    for (int a = 0; a < 8; ++a) {
      for (int s = threadIdx.x; s < nwA[a]; s += 256) w[offW[a] + s] = Wsrc[a][s];
      for (int s = threadIdx.x; s < nbA[a]; s += 256) w[offB[a] + s] = bsrc[a][s];
    }
  }

  const int lane = threadIdx.x & 63;
  const int gid  = blockIdx.x * 256 + threadIdx.x;
  const int pt   = gid >> 3;           // point index (eight lanes per point)
  const int Q    = gid & 3;            // hidden quarter
  const int q    = (gid >> 2) & 1;     // family
  const int hb   = 5 * Q;
  const int hb1  = 5 * (Q ^ 1);
  const int hb2  = 5 * (Q ^ 2);
  const int hb3  = 5 * (Q ^ 3);

  // global min/max: lane l holds block-partial l, butterfly across the wave
  unsigned pmin = mm[2 * lane + 0];
  unsigned pmax = mm[2 * lane + 1];
#pragma unroll
  for (int o = 1; o < 64; o <<= 1) {
    pmin = min(pmin, (unsigned)__shfl_xor((int)pmin, o, 64));
    pmax = max(pmax, (unsigned)__shfl_xor((int)pmax, o, 64));
  }
  float lb = unflip(pmin);
  float ub = unflip(pmax);
  float kk = 2.0f / (ub - lb);

  float x = X[3 * pt], y = X[3 * pt + 1], tt = X[3 * pt + 2];
  float h0 = fmaf(kk, x - lb, -1.0f);
  float h1 = fmaf(kk, y - lb, -1.0f);
  float h2 = fmaf(kk, tt - lb, -1.0f);

  __syncthreads();  // weights staged

  // family-selected seeds (cndmask, no branch)
  float a0s = q ? 0.0f : kk, a1s = q ? kk : 0.0f;  // dA: x-dir / y-dir
  float b1s = q ? -kk : kk;                         // dB: (k,+-k,0)

  // ---- single fused network pass ----
  J9 A[5], B[5];
  {
    J9 T[3];
    {
      J9 I0 = J9::seed(0.f), I1 = J9::seed(0.f), I2 = J9::seed(0.f);
      I0.v = h0; I0.a1 = a0s; I0.b1 = kk;
      I1.v = h1; I1.a1 = a1s; I1.b1 = b1s;
      I2.v = h2; I2.t = kk;
#pragma unroll
      for (int j = 0; j < 3; ++j) {               // L1 3->3, duplicated
        J9 z = J9::seed(w[9 + j]);
        z.macc(w[0 * 3 + j], I0);
        z.macc(w[1 * 3 + j], I1);
        z.macc(w[2 * 3 + j], I2);
        T[j] = z.chain();
      }
    }
#pragma unroll
    for (int j = 0; j < 5; ++j) {                 // L2 3->20, split by quarter
      J9 z = J9::seed(w[72 + hb + j]);
#pragma unroll
      for (int i = 0; i < 3; ++i) z.macc(w[12 + i * 20 + hb + j], T[i]);
      A[j] = z.chain();
    }
  }
#pragma unroll 1
  for (int l = 0; l < 5; ++l) {                   // L3..L7, one hot body
    const float* Wl = w + 92 + l * 420;
    layer20_q(Wl, Wl + 400, hb, hb1, hb2, hb3, A, B);
#pragma unroll
    for (int jj = 0; jj < 5; ++jj) A[jj] = B[jj];
  }

  // L8 psi output: full 9-comp partial + intra-quad butterfly
  float rc1, rc2, rc3, s2, s3, rm;
  {
    J9 z = J9::seed(0.f);
#pragma unroll
    for (int ii = 0; ii < 5; ++ii) z.macc(w[2192 + (hb + ii) * 2 + 0], A[ii]);
    redsum<1>(z); redsum<2>(z);
    z.v += w[2232];
    J9 o = z.chain();
    rc1 = o.a1; rc2 = o.a2; rc3 = o.a3;
    s2 = o.b2; s3 = o.b3; rm = o.m;
  }
  // L8 p output: only {v, a1} needed -> 2-float partial
  float rpv, rpc;
  {
    float pv = 0.f, pa = 0.f;
#pragma unroll
    for (int ii = 0; ii < 5; ++ii) {
      float wt = w[2192 + (hb + ii) * 2 + 1];
      pv = fmaf(wt, A[ii].v,  pv);
      pa = fmaf(wt, A[ii].a1, pa);
    }
    pv += qperm<1>(pv); pa += qperm<1>(pa);
    pv += qperm<2>(pv); pa += qperm<2>(pa);
    pv += w[2233];
    float s = fast_tanh(pv);
    rpv = s;
    rpc = fmaf(-s, s, 1.0f) * pa;
  }

  // cross-family exchange (mask 4 -- crosses quads, keep __shfl_xor; cold)
  float psi_y   = __shfl_xor(rc1, 4, 64);
  float psi_yy  = __shfl_xor(rc2, 4, 64);
  float psi_yyy = __shfl_xor(rc3, 4, 64);
  float p_y     = __shfl_xor(rpc, 4, 64);
  float S2m     = __shfl_xor(s2, 4, 64);
  float S3m     = __shfl_xor(s3, 4, 64);
  float mB      = __shfl_xor(rm, 4, 64);   // m- (on q=0 lanes)

  if ((gid & 7) == 0) {
    float psi_x = rc1, psi_xx = rc2, psi_xxx = rc3;
    float p_val = rpv, p_x = rpc;
    float S2p = s2, S3p = s3;

    // polarization identities (spatial + t-polarization)
    float psi_xy  = 0.25f * (S2p - S2m);
    float psi_xxy = (S3p - S3m - 2.0f * psi_yyy) * (1.0f / 6.0f);
    float psi_xyy = (S3p + S3m - 2.0f * psi_xxx) * (1.0f / 6.0f);
    float psi_xt  = 0.5f * (rm + mB);
    float psi_yt  = 0.5f * (rm - mB);

    float u = psi_y, vv = -psi_x;
    float u_x = psi_xy,  u_y = psi_yy,  u_t = psi_yt;
    float v_x = -psi_xx, v_y = -psi_xy, v_t = -psi_xt;
    float u_xx = psi_xxy,  u_yy = psi_yyy;
    float v_xx = -psi_xxx, v_yy = -psi_xyy;

    float lam1 = lam1p[0], lam2 = lam2p[0];
    float f_u = u_t + lam1 * (u * u_x + vv * u_y) + p_x - lam2 * (u_xx + u_yy);
    float f_v = v_t + lam1 * (u * v_x + vv * v_y) + p_y - lam2 * (v_xx + v_yy);

    out[pt] = u;
    out[NPTS + pt] = vv;
    out[2 * NPTS + pt] = p_val;
    out[3 * NPTS + pt] = f_u;
    out[4 * NPTS + pt] = f_v;
  }
}

extern "C" void kernel_launch(void* const* d_in, const int* in_sizes, int n_in,
                              void* d_out, int out_size, void* d_ws, size_t ws_size,
                              hipStream_t stream) {
  (void)in_sizes; (void)n_in; (void)out_size; (void)ws_size;
  const float* X = (const float*)d_in[0];
  const float* W[8]; const float* B[8];
  for (int i = 0; i < 8; ++i) {
    W[i] = (const float*)d_in[1 + 2 * i];
    B[i] = (const float*)d_in[2 + 2 * i];
  }
  const float* lam1 = (const float*)d_in[17];
  const float* lam2 = (const float*)d_in[18];
  unsigned* mm = (unsigned*)d_ws;
  float* out = (float*)d_out;

  hipLaunchKernelGGL(mm_reduce, dim3(MM_BLOCKS), dim3(256), 0, stream, X, mm);
  hipLaunchKernelGGL(pinn_main, dim3(8 * NPTS / 256), dim3(256), 0, stream,
                     X, W[0], B[0], W[1], B[1], W[2], B[2], W[3], B[3],
                     W[4], B[4], W[5], B[5], W[6], B[6], W[7], B[7],
                     lam1, lam2, mm, out);
}